// Round 6
// baseline (1346.811 us; speedup 1.0000x reference)
//
#include <hip/hip_runtime.h>

// 6-layer pre-LN encoder, B=8 S=1024 D=512 H=8 DH=64 FFN=2048.
// Round 6: attention v3 — no K/V LDS staging (direct global->reg fragment
// loads, L2-resident via XCD-bijective remap), zero barriers in kv loop,
// granule-XOR P buffer. GEMMs unchanged from round 5.

#define SEQ 1024
#define ROWS 8192
#define QKVW 1536

using bf16x8 = __attribute__((ext_vector_type(8))) short;
using f32x4  = __attribute__((ext_vector_type(4))) float;

__device__ __forceinline__ unsigned short f2bf(float f) {
  union { float f; unsigned u; } v; v.f = f;
  unsigned r = v.u + 0x7FFFu + ((v.u >> 16) & 1u);   // RNE
  return (unsigned short)(r >> 16);
}

__device__ __forceinline__ float exp2_fast(float x) {
  float r;
  asm("v_exp_f32 %0, %1" : "=v"(r) : "v"(x));
  return r;
}

__device__ __forceinline__ void gl16(const void* g, void* l) {
  typedef const unsigned int __attribute__((address_space(1)))* GP;
  typedef unsigned int __attribute__((address_space(3)))* LP;
  __builtin_amdgcn_global_load_lds((GP)g, (LP)l, 16, 0, 0);
}

// ---------------------------------------------------------------- weight prep
__global__ __launch_bounds__(256) void transpose_cast_k(
    const float* __restrict__ W, unsigned short* __restrict__ Wt,
    int K, int N, int lstride, float scale)
{
  __shared__ float tile[32][33];
  const int l = blockIdx.z;
  const float* Wl = W + (size_t)l * K * N;
  unsigned short* Wtl = Wt + (size_t)l * lstride;
  const int k0 = blockIdx.y * 32, n0 = blockIdx.x * 32;
  const int tx = threadIdx.x & 31, ty = threadIdx.x >> 5;
  #pragma unroll
  for (int i = ty; i < 32; i += 8)
    tile[i][tx] = Wl[(size_t)(k0 + i) * N + n0 + tx];
  __syncthreads();
  #pragma unroll
  for (int i = ty; i < 32; i += 8)
    Wtl[(size_t)(n0 + i) * K + k0 + tx] = f2bf(tile[tx][i] * scale);
}

// ---------------------------------------------------------------- layernorm
__global__ __launch_bounds__(256) void ln_k(
    const float* __restrict__ x, const float* __restrict__ g,
    const float* __restrict__ be, unsigned short* __restrict__ y, int rows)
{
  const int wid = (blockIdx.x << 2) | (threadIdx.x >> 6);
  const int lane = threadIdx.x & 63;
  if (wid >= rows) return;
  const float4* xr = reinterpret_cast<const float4*>(x + (size_t)wid * 512);
  float4 a = xr[lane];
  float4 b = xr[lane + 64];
  float s = a.x + a.y + a.z + a.w + b.x + b.y + b.z + b.w;
  #pragma unroll
  for (int m = 32; m >= 1; m >>= 1) s += __shfl_xor(s, m);
  const float mu = s * (1.0f / 512.0f);
  const float d0 = a.x - mu, d1 = a.y - mu, d2 = a.z - mu, d3 = a.w - mu;
  const float e0 = b.x - mu, e1 = b.y - mu, e2 = b.z - mu, e3 = b.w - mu;
  float q = d0*d0 + d1*d1 + d2*d2 + d3*d3 + e0*e0 + e1*e1 + e2*e2 + e3*e3;
  #pragma unroll
  for (int m = 32; m >= 1; m >>= 1) q += __shfl_xor(q, m);
  const float inv = rsqrtf(q * (1.0f / 512.0f) + 1e-3f);
  const float4* gr = reinterpret_cast<const float4*>(g);
  const float4* br = reinterpret_cast<const float4*>(be);
  const float4 g0 = gr[lane], g1 = gr[lane + 64];
  const float4 h0 = br[lane], h1 = br[lane + 64];
  ushort4 o0, o1;
  o0.x = f2bf(d0 * inv * g0.x + h0.x);
  o0.y = f2bf(d1 * inv * g0.y + h0.y);
  o0.z = f2bf(d2 * inv * g0.z + h0.z);
  o0.w = f2bf(d3 * inv * g0.w + h0.w);
  o1.x = f2bf(e0 * inv * g1.x + h1.x);
  o1.y = f2bf(e1 * inv * g1.y + h1.y);
  o1.z = f2bf(e2 * inv * g1.z + h1.z);
  o1.w = f2bf(e3 * inv * g1.w + h1.w);
  *reinterpret_cast<ushort4*>(y + (size_t)wid * 512 + lane * 4) = o0;
  *reinterpret_cast<ushort4*>(y + (size_t)wid * 512 + (lane + 64) * 4) = o1;
}

// ---------------------------------------------------------------- GEMM 128x128, BK=32, dbuf 2-phase
template<bool RELU, bool HASBIAS, bool HASRES, bool OUTBF>
__global__ __launch_bounds__(256) void gemm128_k(
    const unsigned short* __restrict__ A,
    const unsigned short* __restrict__ Wt,
    const float* __restrict__ bias,
    const float* __restrict__ res,
    void* __restrict__ outp, int M, int N, int K)
{
  __shared__ __align__(16) unsigned short As0[4096], Bs0[4096];
  __shared__ __align__(16) unsigned short As1[4096], Bs1[4096];
  const int t = threadIdx.x;
  const int nwg = gridDim.x * gridDim.y;
  const int bid = blockIdx.y * gridDim.x + blockIdx.x;
  const int nid = (bid & 7) * (nwg >> 3) + (bid >> 3);
  const int bx = nid % gridDim.x, by = nid / gridDim.x;
  const int m0 = by * 128, n0 = bx * 128;
  const int w = t >> 6, lane = t & 63, llo = lane & 15, lhi = lane >> 4;
  const int wr = w >> 1, wc = w & 1;

  const int sr = t >> 2, sg = (t & 3) ^ ((t >> 3) & 3);
  const unsigned short* pa = &A[(size_t)(m0 + sr) * K + sg * 8];
  const unsigned short* pb = &Wt[(size_t)(n0 + sr) * K + sg * 8];

#define GSTAGE128(AsX, BsX, koff) do { \
    gl16(pa + (koff), &AsX[t * 8]); \
    gl16(pa + (size_t)64 * K + (koff), &AsX[2048 + t * 8]); \
    gl16(pb + (koff), &BsX[t * 8]); \
    gl16(pb + (size_t)64 * K + (koff), &BsX[2048 + t * 8]); \
  } while (0)

  const int pgo = (lhi ^ ((llo >> 1) & 3)) * 8;

#define GCOMP128(AsX, BsX) do { \
    bf16x8 af[4], bfr[4]; \
    _Pragma("unroll") \
    for (int f = 0; f < 4; f++) { \
      af[f]  = *reinterpret_cast<const bf16x8*>(&AsX[(wr * 64 + f * 16 + llo) * 32 + pgo]); \
      bfr[f] = *reinterpret_cast<const bf16x8*>(&BsX[(wc * 64 + f * 16 + llo) * 32 + pgo]); \
    } \
    _Pragma("unroll") \
    for (int fi = 0; fi < 4; fi++) \
      _Pragma("unroll") \
      for (int fj = 0; fj < 4; fj++) \
        acc[fi][fj] = __builtin_amdgcn_mfma_f32_16x16x32_bf16(af[fi], bfr[fj], acc[fi][fj], 0, 0, 0); \
  } while (0)

  f32x4 acc[4][4] = {};
  GSTAGE128(As0, Bs0, 0);
  for (int k0 = 0; k0 < K; k0 += 64) {
    __syncthreads();
    GSTAGE128(As1, Bs1, k0 + 32);
    GCOMP128(As0, Bs0);
    __syncthreads();
    if (k0 + 64 < K) GSTAGE128(As0, Bs0, k0 + 64);
    GCOMP128(As1, Bs1);
  }
#undef GSTAGE128
#undef GCOMP128

  const int row0 = m0 + wr * 64, col0 = n0 + wc * 64;
  #pragma unroll
  for (int fi = 0; fi < 4; fi++)
    #pragma unroll
    for (int fj = 0; fj < 4; fj++)
      #pragma unroll
      for (int i = 0; i < 4; i++) {
        const int row = row0 + fi * 16 + lhi * 4 + i;
        const int col = col0 + fj * 16 + llo;
        float v = acc[fi][fj][i];
        if (HASBIAS) v += bias[col];
        if (HASRES)  v += res[(size_t)row * N + col];
        if (RELU)    v = fmaxf(v, 0.0f);
        if (OUTBF) ((unsigned short*)outp)[(size_t)row * N + col] = f2bf(v);
        else       ((float*)outp)[(size_t)row * N + col] = v;
      }
}

// ---------------------------------------------------------------- GEMM 64x128, BK=32, dbuf 2-phase
template<bool RELU, bool HASBIAS, bool HASRES, bool OUTBF>
__global__ __launch_bounds__(256) void gemm64_k(
    const unsigned short* __restrict__ A,
    const unsigned short* __restrict__ Wt,
    const float* __restrict__ bias,
    const float* __restrict__ res,
    void* __restrict__ outp, int M, int N, int K)
{
  __shared__ __align__(16) unsigned short As0[2048], Bs0[4096];
  __shared__ __align__(16) unsigned short As1[2048], Bs1[4096];
  const int t = threadIdx.x;
  const int nwg = gridDim.x * gridDim.y;
  const int bid = blockIdx.y * gridDim.x + blockIdx.x;
  const int nid = (bid & 7) * (nwg >> 3) + (bid >> 3);
  const int bx = nid % gridDim.x, by = nid / gridDim.x;
  const int m0 = by * 64, n0 = bx * 128;
  const int w = t >> 6, lane = t & 63, llo = lane & 15, lhi = lane >> 4;
  const int wr = w >> 1, wc = w & 1;

  const int sr = t >> 2, sg = (t & 3) ^ ((t >> 3) & 3);
  const unsigned short* pa = &A[(size_t)(m0 + sr) * K + sg * 8];
  const unsigned short* pb = &Wt[(size_t)(n0 + sr) * K + sg * 8];

#define GSTAGE64(AsX, BsX, koff) do { \
    gl16(pa + (koff), &AsX[t * 8]); \
    gl16(pb + (koff), &BsX[t * 8]); \
    gl16(pb + (size_t)64 * K + (koff), &BsX[2048 + t * 8]); \
  } while (0)

  const int pgo = (lhi ^ ((llo >> 1) & 3)) * 8;

#define GCOMP64(AsX, BsX) do { \
    bf16x8 af[2], bfr[4]; \
    _Pragma("unroll") \
    for (int f = 0; f < 2; f++) \
      af[f] = *reinterpret_cast<const bf16x8*>(&AsX[(wr * 32 + f * 16 + llo) * 32 + pgo]); \
    _Pragma("unroll") \
    for (int f = 0; f < 4; f++) \
      bfr[f] = *reinterpret_cast<const bf16x8*>(&BsX[(wc * 64 + f * 16 + llo) * 32 + pgo]); \
    _Pragma("unroll") \
    for (int fi = 0; fi < 2; fi++) \
      _Pragma("unroll") \
      for (int fj = 0; fj < 4; fj++) \
        acc[fi][fj] = __builtin_amdgcn_mfma_f32_16x16x32_bf16(af[fi], bfr[fj], acc[fi][fj], 0, 0, 0); \
  } while (0)

  f32x4 acc[2][4] = {};
  GSTAGE64(As0, Bs0, 0);
  for (int k0 = 0; k0 < K; k0 += 64) {
    __syncthreads();
    GSTAGE64(As1, Bs1, k0 + 32);
    GCOMP64(As0, Bs0);
    __syncthreads();
    if (k0 + 64 < K) GSTAGE64(As0, Bs0, k0 + 64);
    GCOMP64(As1, Bs1);
  }
#undef GSTAGE64
#undef GCOMP64

  const int row0 = m0 + wr * 32, col0 = n0 + wc * 64;
  #pragma unroll
  for (int fi = 0; fi < 2; fi++)
    #pragma unroll
    for (int fj = 0; fj < 4; fj++)
      #pragma unroll
      for (int i = 0; i < 4; i++) {
        const int row = row0 + fi * 16 + lhi * 4 + i;
        const int col = col0 + fj * 16 + llo;
        float v = acc[fi][fj][i];
        if (HASBIAS) v += bias[col];
        if (HASRES)  v += res[(size_t)row * N + col];
        if (RELU)    v = fmaxf(v, 0.0f);
        if (OUTBF) ((unsigned short*)outp)[(size_t)row * N + col] = f2bf(v);
        else       ((float*)outp)[(size_t)row * N + col] = v;
      }
}

// ---------------------------------------------------------------- V transpose
__global__ __launch_bounds__(256) void vtrans_k(
    const unsigned short* __restrict__ QKV, unsigned short* __restrict__ VT)
{
  __shared__ unsigned short tile[64][66];
  const int kt = blockIdx.x, bh = blockIdx.y;
  const int bb = bh >> 3, h = bh & 7;
  const int t = threadIdx.x;
  const int r = t >> 2, c0 = (t & 3) * 16;
  const unsigned short* src = &QKV[((size_t)bb * SEQ + kt * 64 + r) * QKVW + 1024 + h * 64 + c0];
  *reinterpret_cast<uint4*>(&tile[r][c0])     = *reinterpret_cast<const uint4*>(src);
  *reinterpret_cast<uint4*>(&tile[r][c0 + 8]) = *reinterpret_cast<const uint4*>(src + 8);
  __syncthreads();
  const int dv = t >> 2, kv0 = (t & 3) * 16;
  unsigned short tmp[16];
  #pragma unroll
  for (int j = 0; j < 16; j++) tmp[j] = tile[kv0 + j][dv];
  ushort4 o0, o1, o2, o3;
  o0.x = tmp[0];  o0.y = tmp[1];  o0.z = tmp[2];  o0.w = tmp[3];
  o1.x = tmp[4];  o1.y = tmp[5];  o1.z = tmp[6];  o1.w = tmp[7];
  o2.x = tmp[8];  o2.y = tmp[9];  o2.z = tmp[10]; o2.w = tmp[11];
  o3.x = tmp[12]; o3.y = tmp[13]; o3.z = tmp[14]; o3.w = tmp[15];
  unsigned short* dst = &VT[((size_t)bh * 64 + dv) * SEQ + kt * 64 + kv0];
  *reinterpret_cast<ushort4*>(dst)      = o0;
  *reinterpret_cast<ushort4*>(dst + 4)  = o1;
  *reinterpret_cast<ushort4*>(dst + 8)  = o2;
  *reinterpret_cast<ushort4*>(dst + 12) = o3;
}

// ---------------------------------------------------------------- attention v3
// 1024 blocks (XCD-bijective: all 16 q-tiles of a (b,h) on one XCD), 4 waves
// x 16 q-rows. K/V fragments loaded DIRECT global->VGPR (L2-resident, no LDS,
// no barriers). P round-trip through per-wave LDS with granule-XOR. Static-max
// log2-domain softmax (Q pre-scaled by 0.125*log2e, acc init -16).
__global__ __launch_bounds__(256) void attn_k(
    const unsigned short* __restrict__ QKV,   // [8192][1536]
    const unsigned short* __restrict__ VT,    // [bh][64][1024]
    unsigned short* __restrict__ Zb)          // [8192][512]
{
  __shared__ __align__(16) unsigned short Ps[4096];   // 4 waves x 1024

  const int t = threadIdx.x;
  // block n -> XCD n&7; give each XCD 8 whole (b,h) groups
  const int n = blockIdx.x;
  const int m = n >> 3;
  const int g = (n & 7) + 8 * (m >> 4);   // bh group 0..63
  const int qt = m & 15;
  const int h = g & 7, bb = g >> 3;
  const int w = t >> 6, lane = t & 63, llo = lane & 15, lhi = lane >> 4;
  const size_t rowb = (size_t)bb * SEQ;
  const size_t vtb = (size_t)g * 64 * SEQ;

  // hoist Q fragments (0.125*log2e folded into Wq)
  bf16x8 aq[2];
  #pragma unroll
  for (int ds = 0; ds < 2; ds++)
    aq[ds] = *reinterpret_cast<const bf16x8*>(
        &QKV[(rowb + qt * 64 + w * 16 + llo) * QKVW + h * 64 + ds * 32 + lhi * 8]);

  // per-lane K/V fragment row pointers (16B-aligned, contiguous per lane)
  const unsigned short* kR[4];
  const unsigned short* vR[4];
  #pragma unroll
  for (int f = 0; f < 4; f++) {
    kR[f] = &QKV[(rowb + f * 16 + llo) * QKVW + 512 + h * 64 + lhi * 8];
    vR[f] = &VT[vtb + (size_t)(f * 16 + llo) * SEQ + lhi * 8];
  }

  const int pwr = w * 1024;
  const int prd = (lane ^ ((lane >> 2) & 3)) * 8;   // read granule (XOR-swizzled)
  const int wgb = ((llo >> 3)) * 16;                // write granule base bits

  float l_[4] = {0.0f, 0.0f, 0.0f, 0.0f};
  f32x4 o_[4] = {};

  for (int kt = 0; kt < 16; kt++) {
    const int ko = kt * 64;
    // direct K/V fragment loads (bk: [kv=f*16+llo][k=ds*32+lhi*8..+8])
    bf16x8 bk[2][4], bv[2][4];
    #pragma unroll
    for (int ds = 0; ds < 2; ds++)
      #pragma unroll
      for (int f = 0; f < 4; f++) {
        bk[ds][f] = *reinterpret_cast<const bf16x8*>(kR[f] + (size_t)ko * QKVW + ds * 32);
        bv[ds][f] = *reinterpret_cast<const bf16x8*>(vR[f] + ko + ds * 32);
      }

    // QK^T in log2 domain, acc pre-biased by -M0=-16
    f32x4 s_[4];
    #pragma unroll
    for (int fj = 0; fj < 4; fj++)
      #pragma unroll
      for (int i = 0; i < 4; i++) s_[fj][i] = -16.0f;
    #pragma unroll
    for (int ds = 0; ds < 2; ds++)
      #pragma unroll
      for (int fj = 0; fj < 4; fj++)
        s_[fj] = __builtin_amdgcn_mfma_f32_16x16x32_bf16(aq[ds], bk[ds][fj], s_[fj], 0, 0, 0);

    // P = exp2(s), accumulate l per-lane, write bf16 P frags (granule-XOR)
    #pragma unroll
    for (int fj = 0; fj < 4; fj++)
      #pragma unroll
      for (int i = 0; i < 4; i++) {
        const float p = exp2_fast(s_[fj][i]);
        l_[i] += p;
        const int gsub = ((fj & 1) * 2) * 16 + wgb + lhi * 4 + i;   // logical granule
        const int phys = gsub ^ lhi;                                 // XOR low2 bits
        Ps[pwr + (fj >> 1) * 512 + phys * 8 + (llo & 7)] = f2bf(p);
      }

    // PV: O[q 16][dv 64] += P @ V
    #pragma unroll
    for (int ks = 0; ks < 2; ks++) {
      bf16x8 ap = *reinterpret_cast<const bf16x8*>(&Ps[pwr + ks * 512 + prd]);
      #pragma unroll
      for (int fo = 0; fo < 4; fo++)
        o_[fo] = __builtin_amdgcn_mfma_f32_16x16x32_bf16(ap, bv[ks][fo], o_[fo], 0, 0, 0);
    }
  }

  // single end-of-loop l reduction across the 16 column-lanes
  #pragma unroll
  for (int i = 0; i < 4; i++) {
    l_[i] += __shfl_xor(l_[i], 1);
    l_[i] += __shfl_xor(l_[i], 2);
    l_[i] += __shfl_xor(l_[i], 4);
    l_[i] += __shfl_xor(l_[i], 8);
  }

  #pragma unroll
  for (int fo = 0; fo < 4; fo++)
    #pragma unroll
    for (int i = 0; i < 4; i++) {
      const float v = o_[fo][i] / l_[i];
      Zb[(rowb + qt * 64 + w * 16 + lhi * 4 + i) * 512 + h * 64 + fo * 16 + llo] = f2bf(v);
    }
}

// ---------------------------------------------------------------- driver
extern "C" void kernel_launch(void* const* d_in, const int* in_sizes, int n_in,
                              void* d_out, int out_size, void* d_ws, size_t ws_size,
                              hipStream_t stream)
{
  const float* x   = (const float*)d_in[0];
  const float* Wq  = (const float*)d_in[1];
  const float* Wk  = (const float*)d_in[2];
  const float* Wv  = (const float*)d_in[3];
  const float* Wo  = (const float*)d_in[4];
  const float* W1  = (const float*)d_in[5];
  const float* b1  = (const float*)d_in[6];
  const float* W2  = (const float*)d_in[7];
  const float* b2  = (const float*)d_in[8];
  const float* ga  = (const float*)d_in[9];
  const float* ba  = (const float*)d_in[10];
  const float* gf  = (const float*)d_in[11];
  const float* bfn = (const float*)d_in[12];
  float* out = (float*)d_out;

  char* p = (char*)d_ws;
  auto alloc = [&](size_t bytes) { void* r = (void*)p; p += (bytes + 255) & ~(size_t)255; return r; };
  float* E0 = (float*)alloc((size_t)ROWS * 512 * 4);
  float* E1 = (float*)alloc((size_t)ROWS * 512 * 4);
  unsigned short* Ybf   = (unsigned short*)alloc((size_t)ROWS * 512 * 2);
  unsigned short* QKVbf = (unsigned short*)alloc((size_t)ROWS * QKVW * 2);
  unsigned short* H1bf  = (unsigned short*)alloc((size_t)ROWS * 2048 * 2);
  unsigned short* VT    = H1bf;   // aliases front 8MB of H1bf (disjoint in time)
  unsigned short* WtQKV = (unsigned short*)alloc(6ull * QKVW * 512 * 2);
  unsigned short* WtO   = (unsigned short*)alloc(6ull * 512 * 512 * 2);
  unsigned short* Wt1   = (unsigned short*)alloc(6ull * 2048 * 512 * 2);
  unsigned short* Wt2   = (unsigned short*)alloc(6ull * 512 * 2048 * 2);
  unsigned short* Zbf   = Ybf;

  // weight prep (Wq carries softmax scale AND log2e for exp2-domain softmax)
  const float qscale = 0.125f * 1.44269504f;
  transpose_cast_k<<<dim3(16, 16, 6), 256, 0, stream>>>(Wq, WtQKV,          512, 512,  QKVW * 512, qscale);
  transpose_cast_k<<<dim3(16, 16, 6), 256, 0, stream>>>(Wk, WtQKV + 262144, 512, 512,  QKVW * 512, 1.0f);
  transpose_cast_k<<<dim3(16, 16, 6), 256, 0, stream>>>(Wv, WtQKV + 524288, 512, 512,  QKVW * 512, 1.0f);
  transpose_cast_k<<<dim3(16, 16, 6), 256, 0, stream>>>(Wo, WtO,            512, 512,  262144,     1.0f);
  transpose_cast_k<<<dim3(64, 16, 6), 256, 0, stream>>>(W1, Wt1,            512, 2048, 1048576,    1.0f);
  transpose_cast_k<<<dim3(16, 64, 6), 256, 0, stream>>>(W2, Wt2,            2048, 512, 1048576,    1.0f);

  for (int l = 0; l < 6; l++) {
    const float* enc = (l == 0) ? x : E0;
    // pre-LN attention
    ln_k<<<2048, 256, 0, stream>>>(enc, ga + l * 512, ba + l * 512, Ybf, ROWS);
    gemm128_k<false, false, false, true><<<dim3(12, 64), 256, 0, stream>>>(
        Ybf, WtQKV + (size_t)l * QKVW * 512, nullptr, nullptr, QKVbf, ROWS, QKVW, 512);
    vtrans_k<<<dim3(16, 64), 256, 0, stream>>>(QKVbf, VT);
    attn_k<<<dim3(1024), 256, 0, stream>>>(QKVbf, VT, Zbf);
    gemm64_k<false, false, true, false><<<dim3(4, 128), 256, 0, stream>>>(
        Zbf, WtO + (size_t)l * 262144, nullptr, enc, E1, ROWS, 512, 512);
    // pre-LN FFN
    ln_k<<<2048, 256, 0, stream>>>(E1, gf + l * 512, bfn + l * 512, Ybf, ROWS);
    gemm128_k<true, true, false, true><<<dim3(16, 64), 256, 0, stream>>>(
        Ybf, Wt1 + (size_t)l * 1048576, b1 + l * 2048, nullptr, H1bf, ROWS, 2048, 512);
    gemm64_k<false, true, true, false><<<dim3(4, 128), 256, 0, stream>>>(
        H1bf, Wt2 + (size_t)l * 1048576, b2 + l * 512, E1, (l == 5) ? out : E0,
        ROWS, 512, 2048);
  }
}

// Round 7
// 926.501 us; speedup vs baseline: 1.4537x; 1.4537x over previous
//
#include <hip/hip_runtime.h>

// 6-layer pre-LN encoder, B=8 S=1024 D=512 H=8 DH=64 FFN=2048.
// Round 7: revert attention to round-5 structure (LDS dbuf staging — the
// direct-L2 variant was latency-bound at 123us). N=512 GEMMs go to 64x64
// tiles (grid 1024, 4 blocks/CU vs 2). XCD remap fixed to by=bid%gy so
// same-A-panel blocks truly share an XCD L2.

#define SEQ 1024
#define ROWS 8192
#define QKVW 1536

using bf16x8 = __attribute__((ext_vector_type(8))) short;
using f32x4  = __attribute__((ext_vector_type(4))) float;

__device__ __forceinline__ unsigned short f2bf(float f) {
  union { float f; unsigned u; } v; v.f = f;
  unsigned r = v.u + 0x7FFFu + ((v.u >> 16) & 1u);   // RNE
  return (unsigned short)(r >> 16);
}

__device__ __forceinline__ float exp2_fast(float x) {
  float r;
  asm("v_exp_f32 %0, %1" : "=v"(r) : "v"(x));
  return r;
}

__device__ __forceinline__ void gl16(const void* g, void* l) {
  typedef const unsigned int __attribute__((address_space(1)))* GP;
  typedef unsigned int __attribute__((address_space(3)))* LP;
  __builtin_amdgcn_global_load_lds((GP)g, (LP)l, 16, 0, 0);
}

// ---------------------------------------------------------------- weight prep
__global__ __launch_bounds__(256) void transpose_cast_k(
    const float* __restrict__ W, unsigned short* __restrict__ Wt,
    int K, int N, int lstride, float scale)
{
  __shared__ float tile[32][33];
  const int l = blockIdx.z;
  const float* Wl = W + (size_t)l * K * N;
  unsigned short* Wtl = Wt + (size_t)l * lstride;
  const int k0 = blockIdx.y * 32, n0 = blockIdx.x * 32;
  const int tx = threadIdx.x & 31, ty = threadIdx.x >> 5;
  #pragma unroll
  for (int i = ty; i < 32; i += 8)
    tile[i][tx] = Wl[(size_t)(k0 + i) * N + n0 + tx];
  __syncthreads();
  #pragma unroll
  for (int i = ty; i < 32; i += 8)
    Wtl[(size_t)(n0 + i) * K + k0 + tx] = f2bf(tile[tx][i] * scale);
}

// ---------------------------------------------------------------- layernorm
__global__ __launch_bounds__(256) void ln_k(
    const float* __restrict__ x, const float* __restrict__ g,
    const float* __restrict__ be, unsigned short* __restrict__ y, int rows)
{
  const int wid = (blockIdx.x << 2) | (threadIdx.x >> 6);
  const int lane = threadIdx.x & 63;
  if (wid >= rows) return;
  const float4* xr = reinterpret_cast<const float4*>(x + (size_t)wid * 512);
  float4 a = xr[lane];
  float4 b = xr[lane + 64];
  float s = a.x + a.y + a.z + a.w + b.x + b.y + b.z + b.w;
  #pragma unroll
  for (int m = 32; m >= 1; m >>= 1) s += __shfl_xor(s, m);
  const float mu = s * (1.0f / 512.0f);
  const float d0 = a.x - mu, d1 = a.y - mu, d2 = a.z - mu, d3 = a.w - mu;
  const float e0 = b.x - mu, e1 = b.y - mu, e2 = b.z - mu, e3 = b.w - mu;
  float q = d0*d0 + d1*d1 + d2*d2 + d3*d3 + e0*e0 + e1*e1 + e2*e2 + e3*e3;
  #pragma unroll
  for (int m = 32; m >= 1; m >>= 1) q += __shfl_xor(q, m);
  const float inv = rsqrtf(q * (1.0f / 512.0f) + 1e-3f);
  const float4* gr = reinterpret_cast<const float4*>(g);
  const float4* br = reinterpret_cast<const float4*>(be);
  const float4 g0 = gr[lane], g1 = gr[lane + 64];
  const float4 h0 = br[lane], h1 = br[lane + 64];
  ushort4 o0, o1;
  o0.x = f2bf(d0 * inv * g0.x + h0.x);
  o0.y = f2bf(d1 * inv * g0.y + h0.y);
  o0.z = f2bf(d2 * inv * g0.z + h0.z);
  o0.w = f2bf(d3 * inv * g0.w + h0.w);
  o1.x = f2bf(e0 * inv * g1.x + h1.x);
  o1.y = f2bf(e1 * inv * g1.y + h1.y);
  o1.z = f2bf(e2 * inv * g1.z + h1.z);
  o1.w = f2bf(e3 * inv * g1.w + h1.w);
  *reinterpret_cast<ushort4*>(y + (size_t)wid * 512 + lane * 4) = o0;
  *reinterpret_cast<ushort4*>(y + (size_t)wid * 512 + (lane + 64) * 4) = o1;
}

// ---------------------------------------------------------------- GEMM 128x128, BK=32, dbuf 2-phase
template<bool RELU, bool HASBIAS, bool HASRES, bool OUTBF>
__global__ __launch_bounds__(256) void gemm128_k(
    const unsigned short* __restrict__ A,
    const unsigned short* __restrict__ Wt,
    const float* __restrict__ bias,
    const float* __restrict__ res,
    void* __restrict__ outp, int M, int N, int K)
{
  __shared__ __align__(16) unsigned short As0[4096], Bs0[4096];
  __shared__ __align__(16) unsigned short As1[4096], Bs1[4096];
  const int t = threadIdx.x;
  // XCD remap: by = bid % gy (gy % 8 == 0) -> same-A-panel blocks co-XCD
  const int bid = blockIdx.y * gridDim.x + blockIdx.x;
  const int by = bid % gridDim.y, bx = bid / gridDim.y;
  const int m0 = by * 128, n0 = bx * 128;
  const int w = t >> 6, lane = t & 63, llo = lane & 15, lhi = lane >> 4;
  const int wr = w >> 1, wc = w & 1;

  const int sr = t >> 2, sg = (t & 3) ^ ((t >> 3) & 3);
  const unsigned short* pa = &A[(size_t)(m0 + sr) * K + sg * 8];
  const unsigned short* pb = &Wt[(size_t)(n0 + sr) * K + sg * 8];

#define GSTAGE128(AsX, BsX, koff) do { \
    gl16(pa + (koff), &AsX[t * 8]); \
    gl16(pa + (size_t)64 * K + (koff), &AsX[2048 + t * 8]); \
    gl16(pb + (koff), &BsX[t * 8]); \
    gl16(pb + (size_t)64 * K + (koff), &BsX[2048 + t * 8]); \
  } while (0)

  const int pgo = (lhi ^ ((llo >> 1) & 3)) * 8;

#define GCOMP128(AsX, BsX) do { \
    bf16x8 af[4], bfr[4]; \
    _Pragma("unroll") \
    for (int f = 0; f < 4; f++) { \
      af[f]  = *reinterpret_cast<const bf16x8*>(&AsX[(wr * 64 + f * 16 + llo) * 32 + pgo]); \
      bfr[f] = *reinterpret_cast<const bf16x8*>(&BsX[(wc * 64 + f * 16 + llo) * 32 + pgo]); \
    } \
    _Pragma("unroll") \
    for (int fi = 0; fi < 4; fi++) \
      _Pragma("unroll") \
      for (int fj = 0; fj < 4; fj++) \
        acc[fi][fj] = __builtin_amdgcn_mfma_f32_16x16x32_bf16(af[fi], bfr[fj], acc[fi][fj], 0, 0, 0); \
  } while (0)

  f32x4 acc[4][4] = {};
  GSTAGE128(As0, Bs0, 0);
  for (int k0 = 0; k0 < K; k0 += 64) {
    __syncthreads();
    GSTAGE128(As1, Bs1, k0 + 32);
    GCOMP128(As0, Bs0);
    __syncthreads();
    if (k0 + 64 < K) GSTAGE128(As0, Bs0, k0 + 64);
    GCOMP128(As1, Bs1);
  }
#undef GSTAGE128
#undef GCOMP128

  const int row0 = m0 + wr * 64, col0 = n0 + wc * 64;
  #pragma unroll
  for (int fi = 0; fi < 4; fi++)
    #pragma unroll
    for (int fj = 0; fj < 4; fj++)
      #pragma unroll
      for (int i = 0; i < 4; i++) {
        const int row = row0 + fi * 16 + lhi * 4 + i;
        const int col = col0 + fj * 16 + llo;
        float v = acc[fi][fj][i];
        if (HASBIAS) v += bias[col];
        if (HASRES)  v += res[(size_t)row * N + col];
        if (RELU)    v = fmaxf(v, 0.0f);
        if (OUTBF) ((unsigned short*)outp)[(size_t)row * N + col] = f2bf(v);
        else       ((float*)outp)[(size_t)row * N + col] = v;
      }
}

// ---------------------------------------------------------------- GEMM 64x64, BK=32, dbuf 2-phase
// For N=512 outputs: grid (8, M/64) = 1024 blocks -> 4 blocks/CU.
template<bool RELU, bool HASBIAS, bool HASRES, bool OUTBF>
__global__ __launch_bounds__(256) void gemm64_k(
    const unsigned short* __restrict__ A,
    const unsigned short* __restrict__ Wt,
    const float* __restrict__ bias,
    const float* __restrict__ res,
    void* __restrict__ outp, int M, int N, int K)
{
  __shared__ __align__(16) unsigned short As0[2048], Bs0[2048];
  __shared__ __align__(16) unsigned short As1[2048], Bs1[2048];
  const int t = threadIdx.x;
  const int bid = blockIdx.y * gridDim.x + blockIdx.x;
  const int by = bid % gridDim.y, bx = bid / gridDim.y;
  const int m0 = by * 64, n0 = bx * 64;
  const int w = t >> 6, lane = t & 63, llo = lane & 15, lhi = lane >> 4;
  const int wr = w >> 1, wc = w & 1;

  const int sr = t >> 2, sg = (t & 3) ^ ((t >> 3) & 3);
  const unsigned short* pa = &A[(size_t)(m0 + sr) * K + sg * 8];
  const unsigned short* pb = &Wt[(size_t)(n0 + sr) * K + sg * 8];

#define GSTAGE64(AsX, BsX, koff) do { \
    gl16(pa + (koff), &AsX[t * 8]); \
    gl16(pb + (koff), &BsX[t * 8]); \
  } while (0)

  const int pgo = (lhi ^ ((llo >> 1) & 3)) * 8;

#define GCOMP64(AsX, BsX) do { \
    bf16x8 af[2], bfr[2]; \
    _Pragma("unroll") \
    for (int f = 0; f < 2; f++) { \
      af[f]  = *reinterpret_cast<const bf16x8*>(&AsX[(wr * 32 + f * 16 + llo) * 32 + pgo]); \
      bfr[f] = *reinterpret_cast<const bf16x8*>(&BsX[(wc * 32 + f * 16 + llo) * 32 + pgo]); \
    } \
    _Pragma("unroll") \
    for (int fi = 0; fi < 2; fi++) \
      _Pragma("unroll") \
      for (int fj = 0; fj < 2; fj++) \
        acc[fi][fj] = __builtin_amdgcn_mfma_f32_16x16x32_bf16(af[fi], bfr[fj], acc[fi][fj], 0, 0, 0); \
  } while (0)

  f32x4 acc[2][2] = {};
  GSTAGE64(As0, Bs0, 0);
  for (int k0 = 0; k0 < K; k0 += 64) {
    __syncthreads();
    GSTAGE64(As1, Bs1, k0 + 32);
    GCOMP64(As0, Bs0);
    __syncthreads();
    if (k0 + 64 < K) GSTAGE64(As0, Bs0, k0 + 64);
    GCOMP64(As1, Bs1);
  }
#undef GSTAGE64
#undef GCOMP64

  const int row0 = m0 + wr * 32, col0 = n0 + wc * 32;
  #pragma unroll
  for (int fi = 0; fi < 2; fi++)
    #pragma unroll
    for (int fj = 0; fj < 2; fj++)
      #pragma unroll
      for (int i = 0; i < 4; i++) {
        const int row = row0 + fi * 16 + lhi * 4 + i;
        const int col = col0 + fj * 16 + llo;
        float v = acc[fi][fj][i];
        if (HASBIAS) v += bias[col];
        if (HASRES)  v += res[(size_t)row * N + col];
        if (RELU)    v = fmaxf(v, 0.0f);
        if (OUTBF) ((unsigned short*)outp)[(size_t)row * N + col] = f2bf(v);
        else       ((float*)outp)[(size_t)row * N + col] = v;
      }
}

// ---------------------------------------------------------------- V transpose
__global__ __launch_bounds__(256) void vtrans_k(
    const unsigned short* __restrict__ QKV, unsigned short* __restrict__ VT)
{
  __shared__ unsigned short tile[64][66];
  const int kt = blockIdx.x, bh = blockIdx.y;
  const int bb = bh >> 3, h = bh & 7;
  const int t = threadIdx.x;
  const int r = t >> 2, c0 = (t & 3) * 16;
  const unsigned short* src = &QKV[((size_t)bb * SEQ + kt * 64 + r) * QKVW + 1024 + h * 64 + c0];
  *reinterpret_cast<uint4*>(&tile[r][c0])     = *reinterpret_cast<const uint4*>(src);
  *reinterpret_cast<uint4*>(&tile[r][c0 + 8]) = *reinterpret_cast<const uint4*>(src + 8);
  __syncthreads();
  const int dv = t >> 2, kv0 = (t & 3) * 16;
  unsigned short tmp[16];
  #pragma unroll
  for (int j = 0; j < 16; j++) tmp[j] = tile[kv0 + j][dv];
  ushort4 o0, o1, o2, o3;
  o0.x = tmp[0];  o0.y = tmp[1];  o0.z = tmp[2];  o0.w = tmp[3];
  o1.x = tmp[4];  o1.y = tmp[5];  o1.z = tmp[6];  o1.w = tmp[7];
  o2.x = tmp[8];  o2.y = tmp[9];  o2.z = tmp[10]; o2.w = tmp[11];
  o3.x = tmp[12]; o3.y = tmp[13]; o3.z = tmp[14]; o3.w = tmp[15];
  unsigned short* dst = &VT[((size_t)bh * 64 + dv) * SEQ + kt * 64 + kv0];
  *reinterpret_cast<ushort4*>(dst)      = o0;
  *reinterpret_cast<ushort4*>(dst + 4)  = o1;
  *reinterpret_cast<ushort4*>(dst + 8)  = o2;
  *reinterpret_cast<ushort4*>(dst + 12) = o3;
}

// ---------------------------------------------------------------- attention (round-5 structure)
// block = (qt 0..15, h, b); 4 waves x 16 q-rows; kv tiles of 64; K/V dbuf
// 2-phase (stage t+1 before compute t, one barrier per tile). Static-max
// log2-domain softmax (Q pre-scaled by 0.125*log2e, acc init -16).
__global__ __launch_bounds__(256) void attn_k(
    const unsigned short* __restrict__ QKV,   // [8192][1536]
    const unsigned short* __restrict__ VT,    // [bh][64][1024]
    unsigned short* __restrict__ Zb)          // [8192][512]
{
  __shared__ __align__(16) unsigned short Ks0[4096], Vs0[4096];
  __shared__ __align__(16) unsigned short Ks1[4096], Vs1[4096];
  __shared__ __align__(16) unsigned short Ps[4096];   // 4 waves x 1024

  const int t = threadIdx.x;
  const int qt = blockIdx.x, h = blockIdx.y, bb = blockIdx.z;
  const int w = t >> 6, lane = t & 63, llo = lane & 15, lhi = lane >> 4;
  const size_t rowb = (size_t)bb * SEQ;
  const int kcol = 512 + h * 64;
  const size_t vtb = (size_t)(bb * 8 + h) * 64 * SEQ;

  // hoist Q fragments (0.125*log2e folded into Wq)
  bf16x8 aq[2];
  #pragma unroll
  for (int ds = 0; ds < 2; ds++)
    aq[ds] = *reinterpret_cast<const bf16x8*>(
        &QKV[(rowb + qt * 64 + w * 16 + llo) * QKVW + h * 64 + ds * 32 + lhi * 8]);

  // frag-major staging sources (chunk c = iss*256 + t)
  const int cA = t, cB = 256 + t;
  const int gA = cA >> 6, lA = cA & 63, gB = cB >> 6, lB = cB & 63;
  const unsigned short* kpA = &QKV[(rowb + (gA >> 1) * 16 + (lA & 15)) * QKVW + kcol + (gA & 1) * 32 + (lA >> 4) * 8];
  const unsigned short* kpB = &QKV[(rowb + (gB >> 1) * 16 + (lB & 15)) * QKVW + kcol + (gB & 1) * 32 + (lB >> 4) * 8];
  const unsigned short* vpA = &VT[vtb + (size_t)((gA >> 1) * 16 + (lA & 15)) * SEQ + (gA & 1) * 32 + (lA >> 4) * 8];
  const unsigned short* vpB = &VT[vtb + (size_t)((gB >> 1) * 16 + (lB & 15)) * SEQ + (gB & 1) * 32 + (lB >> 4) * 8];

#define ASTAGE(KsX, VsX, ktt) do { \
    gl16(kpA + (size_t)(ktt) * 64 * QKVW, &KsX[cA * 8]); \
    gl16(kpB + (size_t)(ktt) * 64 * QKVW, &KsX[cB * 8]); \
    gl16(vpA + (ktt) * 64, &VsX[cA * 8]); \
    gl16(vpB + (ktt) * 64, &VsX[cB * 8]); \
  } while (0)

#define ACOMP(KsX, VsX) do { \
    f32x4 s_[4]; \
    _Pragma("unroll") \
    for (int fj = 0; fj < 4; fj++) \
      _Pragma("unroll") \
      for (int i = 0; i < 4; i++) s_[fj][i] = -16.0f; \
    _Pragma("unroll") \
    for (int ds = 0; ds < 2; ds++) \
      _Pragma("unroll") \
      for (int fj = 0; fj < 4; fj++) { \
        bf16x8 bk = *reinterpret_cast<const bf16x8*>(&KsX[((fj * 2 + ds) * 64 + lane) * 8]); \
        s_[fj] = __builtin_amdgcn_mfma_f32_16x16x32_bf16(aq[ds], bk, s_[fj], 0, 0, 0); \
      } \
    _Pragma("unroll") \
    for (int fj = 0; fj < 4; fj++) \
      _Pragma("unroll") \
      for (int i = 0; i < 4; i++) { \
        const float p = exp2_fast(s_[fj][i]); \
        l_[i] += p; \
        Ps[w * 1024 + (fj >> 1) * 512 + ((fj & 1) * 2 + (llo >> 3)) * 128 \
           + (lhi * 4 + i) * 8 + (llo & 7)] = f2bf(p); \
      } \
    _Pragma("unroll") \
    for (int ks = 0; ks < 2; ks++) { \
      bf16x8 ap = *reinterpret_cast<const bf16x8*>(&Ps[w * 1024 + (ks * 64 + lane) * 8]); \
      _Pragma("unroll") \
      for (int fo = 0; fo < 4; fo++) { \
        bf16x8 bv = *reinterpret_cast<const bf16x8*>(&VsX[((fo * 2 + ks) * 64 + lane) * 8]); \
        o_[fo] = __builtin_amdgcn_mfma_f32_16x16x32_bf16(ap, bv, o_[fo], 0, 0, 0); \
      } \
    } \
  } while (0)

  float l_[4] = {0.0f, 0.0f, 0.0f, 0.0f};
  f32x4 o_[4] = {};

  ASTAGE(Ks0, Vs0, 0);
  for (int kt = 0; kt < 16; kt += 2) {
    __syncthreads();
    ASTAGE(Ks1, Vs1, kt + 1);
    ACOMP(Ks0, Vs0);
    __syncthreads();
    if (kt + 2 < 16) ASTAGE(Ks0, Vs0, kt + 2);
    ACOMP(Ks1, Vs1);
  }
#undef ASTAGE
#undef ACOMP

  // single end-of-loop l reduction across the 16 column-lanes
  #pragma unroll
  for (int i = 0; i < 4; i++) {
    l_[i] += __shfl_xor(l_[i], 1);
    l_[i] += __shfl_xor(l_[i], 2);
    l_[i] += __shfl_xor(l_[i], 4);
    l_[i] += __shfl_xor(l_[i], 8);
  }

  #pragma unroll
  for (int fo = 0; fo < 4; fo++)
    #pragma unroll
    for (int i = 0; i < 4; i++) {
      const float v = o_[fo][i] / l_[i];
      Zb[(rowb + qt * 64 + w * 16 + lhi * 4 + i) * 512 + h * 64 + fo * 16 + llo] = f2bf(v);
    }
}

// ---------------------------------------------------------------- driver
extern "C" void kernel_launch(void* const* d_in, const int* in_sizes, int n_in,
                              void* d_out, int out_size, void* d_ws, size_t ws_size,
                              hipStream_t stream)
{
  const float* x   = (const float*)d_in[0];
  const float* Wq  = (const float*)d_in[1];
  const float* Wk  = (const float*)d_in[2];
  const float* Wv  = (const float*)d_in[3];
  const float* Wo  = (const float*)d_in[4];
  const float* W1  = (const float*)d_in[5];
  const float* b1  = (const float*)d_in[6];
  const float* W2  = (const float*)d_in[7];
  const float* b2  = (const float*)d_in[8];
  const float* ga  = (const float*)d_in[9];
  const float* ba  = (const float*)d_in[10];
  const float* gf  = (const float*)d_in[11];
  const float* bfn = (const float*)d_in[12];
  float* out = (float*)d_out;

  char* p = (char*)d_ws;
  auto alloc = [&](size_t bytes) { void* r = (void*)p; p += (bytes + 255) & ~(size_t)255; return r; };
  float* E0 = (float*)alloc((size_t)ROWS * 512 * 4);
  float* E1 = (float*)alloc((size_t)ROWS * 512 * 4);
  unsigned short* Ybf   = (unsigned short*)alloc((size_t)ROWS * 512 * 2);
  unsigned short* QKVbf = (unsigned short*)alloc((size_t)ROWS * QKVW * 2);
  unsigned short* H1bf  = (unsigned short*)alloc((size_t)ROWS * 2048 * 2);
  unsigned short* VT    = H1bf;   // aliases front 8MB of H1bf (disjoint in time)
  unsigned short* WtQKV = (unsigned short*)alloc(6ull * QKVW * 512 * 2);
  unsigned short* WtO   = (unsigned short*)alloc(6ull * 512 * 512 * 2);
  unsigned short* Wt1   = (unsigned short*)alloc(6ull * 2048 * 512 * 2);
  unsigned short* Wt2   = (unsigned short*)alloc(6ull * 512 * 2048 * 2);
  unsigned short* Zbf   = Ybf;

  // weight prep (Wq carries softmax scale AND log2e for exp2-domain softmax)
  const float qscale = 0.125f * 1.44269504f;
  transpose_cast_k<<<dim3(16, 16, 6), 256, 0, stream>>>(Wq, WtQKV,          512, 512,  QKVW * 512, qscale);
  transpose_cast_k<<<dim3(16, 16, 6), 256, 0, stream>>>(Wk, WtQKV + 262144, 512, 512,  QKVW * 512, 1.0f);
  transpose_cast_k<<<dim3(16, 16, 6), 256, 0, stream>>>(Wv, WtQKV + 524288, 512, 512,  QKVW * 512, 1.0f);
  transpose_cast_k<<<dim3(16, 16, 6), 256, 0, stream>>>(Wo, WtO,            512, 512,  262144,     1.0f);
  transpose_cast_k<<<dim3(64, 16, 6), 256, 0, stream>>>(W1, Wt1,            512, 2048, 1048576,    1.0f);
  transpose_cast_k<<<dim3(16, 64, 6), 256, 0, stream>>>(W2, Wt2,            2048, 512, 1048576,    1.0f);

  for (int l = 0; l < 6; l++) {
    const float* enc = (l == 0) ? x : E0;
    // pre-LN attention
    ln_k<<<2048, 256, 0, stream>>>(enc, ga + l * 512, ba + l * 512, Ybf, ROWS);
    gemm128_k<false, false, false, true><<<dim3(12, 64), 256, 0, stream>>>(
        Ybf, WtQKV + (size_t)l * QKVW * 512, nullptr, nullptr, QKVbf, ROWS, QKVW, 512);
    vtrans_k<<<dim3(16, 64), 256, 0, stream>>>(QKVbf, VT);
    attn_k<<<dim3(16, 8, 8), 256, 0, stream>>>(QKVbf, VT, Zbf);
    gemm64_k<false, false, true, false><<<dim3(8, 128), 256, 0, stream>>>(
        Zbf, WtO + (size_t)l * 262144, nullptr, enc, E1, ROWS, 512, 512);
    // pre-LN FFN
    ln_k<<<2048, 256, 0, stream>>>(E1, gf + l * 512, bfn + l * 512, Ybf, ROWS);
    gemm128_k<true, true, false, true><<<dim3(16, 64), 256, 0, stream>>>(
        Ybf, Wt1 + (size_t)l * 1048576, b1 + l * 2048, nullptr, H1bf, ROWS, 2048, 512);
    gemm64_k<false, true, true, false><<<dim3(8, 128), 256, 0, stream>>>(
        H1bf, Wt2 + (size_t)l * 1048576, b2 + l * 512, E1, (l == 5) ? out : E0,
        ROWS, 512, 2048);
  }
}

// Round 8
// 883.776 us; speedup vs baseline: 1.5239x; 1.0483x over previous
//
#include <hip/hip_runtime.h>

// 6-layer pre-LN encoder, B=8 S=1024 D=512 H=8 DH=64 FFN=2048.
// Round 8: GEMMs reverted to round-5 exact configs (64x128 gemm64, R5
// swizzle). Attention v4: swapped-operand QK^T (S^T = mfma(K,Q)) so P is
// kv-contiguous per lane -> cvt_pk_bf16 pairs + ds_write_b64 into a
// granule-XOR [16][64] per-wave P buffer (conflict-free write+read),
// scalar per-lane l. Static-max log2-domain softmax as before.

#define SEQ 1024
#define ROWS 8192
#define QKVW 1536

using bf16x8 = __attribute__((ext_vector_type(8))) short;
using f32x4  = __attribute__((ext_vector_type(4))) float;

__device__ __forceinline__ unsigned short f2bf(float f) {
  union { float f; unsigned u; } v; v.f = f;
  unsigned r = v.u + 0x7FFFu + ((v.u >> 16) & 1u);   // RNE
  return (unsigned short)(r >> 16);
}

__device__ __forceinline__ float exp2_fast(float x) {
  float r;
  asm("v_exp_f32 %0, %1" : "=v"(r) : "v"(x));
  return r;
}

__device__ __forceinline__ unsigned cvtpk_bf16(float a, float b) {
  unsigned r;   // low16 = bf16(a), high16 = bf16(b)
  asm("v_cvt_pk_bf16_f32 %0, %1, %2" : "=v"(r) : "v"(a), "v"(b));
  return r;
}

__device__ __forceinline__ void gl16(const void* g, void* l) {
  typedef const unsigned int __attribute__((address_space(1)))* GP;
  typedef unsigned int __attribute__((address_space(3)))* LP;
  __builtin_amdgcn_global_load_lds((GP)g, (LP)l, 16, 0, 0);
}

// ---------------------------------------------------------------- weight prep
__global__ __launch_bounds__(256) void transpose_cast_k(
    const float* __restrict__ W, unsigned short* __restrict__ Wt,
    int K, int N, int lstride, float scale)
{
  __shared__ float tile[32][33];
  const int l = blockIdx.z;
  const float* Wl = W + (size_t)l * K * N;
  unsigned short* Wtl = Wt + (size_t)l * lstride;
  const int k0 = blockIdx.y * 32, n0 = blockIdx.x * 32;
  const int tx = threadIdx.x & 31, ty = threadIdx.x >> 5;
  #pragma unroll
  for (int i = ty; i < 32; i += 8)
    tile[i][tx] = Wl[(size_t)(k0 + i) * N + n0 + tx];
  __syncthreads();
  #pragma unroll
  for (int i = ty; i < 32; i += 8)
    Wtl[(size_t)(n0 + i) * K + k0 + tx] = f2bf(tile[tx][i] * scale);
}

// ---------------------------------------------------------------- layernorm
__global__ __launch_bounds__(256) void ln_k(
    const float* __restrict__ x, const float* __restrict__ g,
    const float* __restrict__ be, unsigned short* __restrict__ y, int rows)
{
  const int wid = (blockIdx.x << 2) | (threadIdx.x >> 6);
  const int lane = threadIdx.x & 63;
  if (wid >= rows) return;
  const float4* xr = reinterpret_cast<const float4*>(x + (size_t)wid * 512);
  float4 a = xr[lane];
  float4 b = xr[lane + 64];
  float s = a.x + a.y + a.z + a.w + b.x + b.y + b.z + b.w;
  #pragma unroll
  for (int m = 32; m >= 1; m >>= 1) s += __shfl_xor(s, m);
  const float mu = s * (1.0f / 512.0f);
  const float d0 = a.x - mu, d1 = a.y - mu, d2 = a.z - mu, d3 = a.w - mu;
  const float e0 = b.x - mu, e1 = b.y - mu, e2 = b.z - mu, e3 = b.w - mu;
  float q = d0*d0 + d1*d1 + d2*d2 + d3*d3 + e0*e0 + e1*e1 + e2*e2 + e3*e3;
  #pragma unroll
  for (int m = 32; m >= 1; m >>= 1) q += __shfl_xor(q, m);
  const float inv = rsqrtf(q * (1.0f / 512.0f) + 1e-3f);
  const float4* gr = reinterpret_cast<const float4*>(g);
  const float4* br = reinterpret_cast<const float4*>(be);
  const float4 g0 = gr[lane], g1 = gr[lane + 64];
  const float4 h0 = br[lane], h1 = br[lane + 64];
  ushort4 o0, o1;
  o0.x = f2bf(d0 * inv * g0.x + h0.x);
  o0.y = f2bf(d1 * inv * g0.y + h0.y);
  o0.z = f2bf(d2 * inv * g0.z + h0.z);
  o0.w = f2bf(d3 * inv * g0.w + h0.w);
  o1.x = f2bf(e0 * inv * g1.x + h1.x);
  o1.y = f2bf(e1 * inv * g1.y + h1.y);
  o1.z = f2bf(e2 * inv * g1.z + h1.z);
  o1.w = f2bf(e3 * inv * g1.w + h1.w);
  *reinterpret_cast<ushort4*>(y + (size_t)wid * 512 + lane * 4) = o0;
  *reinterpret_cast<ushort4*>(y + (size_t)wid * 512 + (lane + 64) * 4) = o1;
}

// ---------------------------------------------------------------- GEMM 128x128, BK=32, dbuf 2-phase
template<bool RELU, bool HASBIAS, bool HASRES, bool OUTBF>
__global__ __launch_bounds__(256) void gemm128_k(
    const unsigned short* __restrict__ A,
    const unsigned short* __restrict__ Wt,
    const float* __restrict__ bias,
    const float* __restrict__ res,
    void* __restrict__ outp, int M, int N, int K)
{
  __shared__ __align__(16) unsigned short As0[4096], Bs0[4096];
  __shared__ __align__(16) unsigned short As1[4096], Bs1[4096];
  const int t = threadIdx.x;
  const int nwg = gridDim.x * gridDim.y;
  const int bid = blockIdx.y * gridDim.x + blockIdx.x;
  const int nid = (bid & 7) * (nwg >> 3) + (bid >> 3);
  const int bx = nid % gridDim.x, by = nid / gridDim.x;
  const int m0 = by * 128, n0 = bx * 128;
  const int w = t >> 6, lane = t & 63, llo = lane & 15, lhi = lane >> 4;
  const int wr = w >> 1, wc = w & 1;

  const int sr = t >> 2, sg = (t & 3) ^ ((t >> 3) & 3);
  const unsigned short* pa = &A[(size_t)(m0 + sr) * K + sg * 8];
  const unsigned short* pb = &Wt[(size_t)(n0 + sr) * K + sg * 8];

#define GSTAGE128(AsX, BsX, koff) do { \
    gl16(pa + (koff), &AsX[t * 8]); \
    gl16(pa + (size_t)64 * K + (koff), &AsX[2048 + t * 8]); \
    gl16(pb + (koff), &BsX[t * 8]); \
    gl16(pb + (size_t)64 * K + (koff), &BsX[2048 + t * 8]); \
  } while (0)

  const int pgo = (lhi ^ ((llo >> 1) & 3)) * 8;

#define GCOMP128(AsX, BsX) do { \
    bf16x8 af[4], bfr[4]; \
    _Pragma("unroll") \
    for (int f = 0; f < 4; f++) { \
      af[f]  = *reinterpret_cast<const bf16x8*>(&AsX[(wr * 64 + f * 16 + llo) * 32 + pgo]); \
      bfr[f] = *reinterpret_cast<const bf16x8*>(&BsX[(wc * 64 + f * 16 + llo) * 32 + pgo]); \
    } \
    _Pragma("unroll") \
    for (int fi = 0; fi < 4; fi++) \
      _Pragma("unroll") \
      for (int fj = 0; fj < 4; fj++) \
        acc[fi][fj] = __builtin_amdgcn_mfma_f32_16x16x32_bf16(af[fi], bfr[fj], acc[fi][fj], 0, 0, 0); \
  } while (0)

  f32x4 acc[4][4] = {};
  GSTAGE128(As0, Bs0, 0);
  for (int k0 = 0; k0 < K; k0 += 64) {
    __syncthreads();
    GSTAGE128(As1, Bs1, k0 + 32);
    GCOMP128(As0, Bs0);
    __syncthreads();
    if (k0 + 64 < K) GSTAGE128(As0, Bs0, k0 + 64);
    GCOMP128(As1, Bs1);
  }
#undef GSTAGE128
#undef GCOMP128

  const int row0 = m0 + wr * 64, col0 = n0 + wc * 64;
  #pragma unroll
  for (int fi = 0; fi < 4; fi++)
    #pragma unroll
    for (int fj = 0; fj < 4; fj++)
      #pragma unroll
      for (int i = 0; i < 4; i++) {
        const int row = row0 + fi * 16 + lhi * 4 + i;
        const int col = col0 + fj * 16 + llo;
        float v = acc[fi][fj][i];
        if (HASBIAS) v += bias[col];
        if (HASRES)  v += res[(size_t)row * N + col];
        if (RELU)    v = fmaxf(v, 0.0f);
        if (OUTBF) ((unsigned short*)outp)[(size_t)row * N + col] = f2bf(v);
        else       ((float*)outp)[(size_t)row * N + col] = v;
      }
}

// ---------------------------------------------------------------- GEMM 64x128, BK=32, dbuf 2-phase
template<bool RELU, bool HASBIAS, bool HASRES, bool OUTBF>
__global__ __launch_bounds__(256) void gemm64_k(
    const unsigned short* __restrict__ A,
    const unsigned short* __restrict__ Wt,
    const float* __restrict__ bias,
    const float* __restrict__ res,
    void* __restrict__ outp, int M, int N, int K)
{
  __shared__ __align__(16) unsigned short As0[2048], Bs0[4096];
  __shared__ __align__(16) unsigned short As1[2048], Bs1[4096];
  const int t = threadIdx.x;
  const int nwg = gridDim.x * gridDim.y;
  const int bid = blockIdx.y * gridDim.x + blockIdx.x;
  const int nid = (bid & 7) * (nwg >> 3) + (bid >> 3);
  const int bx = nid % gridDim.x, by = nid / gridDim.x;
  const int m0 = by * 64, n0 = bx * 128;
  const int w = t >> 6, lane = t & 63, llo = lane & 15, lhi = lane >> 4;
  const int wr = w >> 1, wc = w & 1;

  const int sr = t >> 2, sg = (t & 3) ^ ((t >> 3) & 3);
  const unsigned short* pa = &A[(size_t)(m0 + sr) * K + sg * 8];
  const unsigned short* pb = &Wt[(size_t)(n0 + sr) * K + sg * 8];

#define GSTAGE64(AsX, BsX, koff) do { \
    gl16(pa + (koff), &AsX[t * 8]); \
    gl16(pb + (koff), &BsX[t * 8]); \
    gl16(pb + (size_t)64 * K + (koff), &BsX[2048 + t * 8]); \
  } while (0)

  const int pgo = (lhi ^ ((llo >> 1) & 3)) * 8;

#define GCOMP64(AsX, BsX) do { \
    bf16x8 af[2], bfr[4]; \
    _Pragma("unroll") \
    for (int f = 0; f < 2; f++) \
      af[f] = *reinterpret_cast<const bf16x8*>(&AsX[(wr * 32 + f * 16 + llo) * 32 + pgo]); \
    _Pragma("unroll") \
    for (int f = 0; f < 4; f++) \
      bfr[f] = *reinterpret_cast<const bf16x8*>(&BsX[(wc * 64 + f * 16 + llo) * 32 + pgo]); \
    _Pragma("unroll") \
    for (int fi = 0; fi < 2; fi++) \
      _Pragma("unroll") \
      for (int fj = 0; fj < 4; fj++) \
        acc[fi][fj] = __builtin_amdgcn_mfma_f32_16x16x32_bf16(af[fi], bfr[fj], acc[fi][fj], 0, 0, 0); \
  } while (0)

  f32x4 acc[2][4] = {};
  GSTAGE64(As0, Bs0, 0);
  for (int k0 = 0; k0 < K; k0 += 64) {
    __syncthreads();
    GSTAGE64(As1, Bs1, k0 + 32);
    GCOMP64(As0, Bs0);
    __syncthreads();
    if (k0 + 64 < K) GSTAGE64(As0, Bs0, k0 + 64);
    GCOMP64(As1, Bs1);
  }
#undef GSTAGE64
#undef GCOMP64

  const int row0 = m0 + wr * 32, col0 = n0 + wc * 64;
  #pragma unroll
  for (int fi = 0; fi < 2; fi++)
    #pragma unroll
    for (int fj = 0; fj < 4; fj++)
      #pragma unroll
      for (int i = 0; i < 4; i++) {
        const int row = row0 + fi * 16 + lhi * 4 + i;
        const int col = col0 + fj * 16 + llo;
        float v = acc[fi][fj][i];
        if (HASBIAS) v += bias[col];
        if (HASRES)  v += res[(size_t)row * N + col];
        if (RELU)    v = fmaxf(v, 0.0f);
        if (OUTBF) ((unsigned short*)outp)[(size_t)row * N + col] = f2bf(v);
        else       ((float*)outp)[(size_t)row * N + col] = v;
      }
}

// ---------------------------------------------------------------- V transpose
__global__ __launch_bounds__(256) void vtrans_k(
    const unsigned short* __restrict__ QKV, unsigned short* __restrict__ VT)
{
  __shared__ unsigned short tile[64][66];
  const int kt = blockIdx.x, bh = blockIdx.y;
  const int bb = bh >> 3, h = bh & 7;
  const int t = threadIdx.x;
  const int r = t >> 2, c0 = (t & 3) * 16;
  const unsigned short* src = &QKV[((size_t)bb * SEQ + kt * 64 + r) * QKVW + 1024 + h * 64 + c0];
  *reinterpret_cast<uint4*>(&tile[r][c0])     = *reinterpret_cast<const uint4*>(src);
  *reinterpret_cast<uint4*>(&tile[r][c0 + 8]) = *reinterpret_cast<const uint4*>(src + 8);
  __syncthreads();
  const int dv = t >> 2, kv0 = (t & 3) * 16;
  unsigned short tmp[16];
  #pragma unroll
  for (int j = 0; j < 16; j++) tmp[j] = tile[kv0 + j][dv];
  ushort4 o0, o1, o2, o3;
  o0.x = tmp[0];  o0.y = tmp[1];  o0.z = tmp[2];  o0.w = tmp[3];
  o1.x = tmp[4];  o1.y = tmp[5];  o1.z = tmp[6];  o1.w = tmp[7];
  o2.x = tmp[8];  o2.y = tmp[9];  o2.z = tmp[10]; o2.w = tmp[11];
  o3.x = tmp[12]; o3.y = tmp[13]; o3.z = tmp[14]; o3.w = tmp[15];
  unsigned short* dst = &VT[((size_t)bh * 64 + dv) * SEQ + kt * 64 + kv0];
  *reinterpret_cast<ushort4*>(dst)      = o0;
  *reinterpret_cast<ushort4*>(dst + 4)  = o1;
  *reinterpret_cast<ushort4*>(dst + 8)  = o2;
  *reinterpret_cast<ushort4*>(dst + 12) = o3;
}

// ---------------------------------------------------------------- attention v4
// block = (qt, h, b); 4 waves x 16 q-rows; kv tiles of 64; K/V dbuf 2-phase.
// SWAPPED QK^T: S^T = mfma(K,Q) -> lane holds P[kv=fj*16+lhi*4+i][q=llo];
// kv-contiguous 4-chunks -> cvt_pk_bf16 + ds_write_b64 into granule-XOR
// [16][64] per-wave P buffer; per-lane scalar l. Static-max log2 softmax.
__global__ __launch_bounds__(256) void attn_k(
    const unsigned short* __restrict__ QKV,   // [8192][1536]
    const unsigned short* __restrict__ VT,    // [bh][64][1024]
    unsigned short* __restrict__ Zb)          // [8192][512]
{
  __shared__ __align__(16) unsigned short Ks0[4096], Vs0[4096];
  __shared__ __align__(16) unsigned short Ks1[4096], Vs1[4096];
  __shared__ __align__(16) unsigned short Ps[4096];   // 4 waves x [16][64]

  const int t = threadIdx.x;
  const int qt = blockIdx.x, h = blockIdx.y, bb = blockIdx.z;
  const int w = t >> 6, lane = t & 63, llo = lane & 15, lhi = lane >> 4;
  const size_t rowb = (size_t)bb * SEQ;
  const int kcol = 512 + h * 64;
  const size_t vtb = (size_t)(bb * 8 + h) * 64 * SEQ;

  // hoist Q fragments (0.125*log2e folded into Wq)
  bf16x8 aq[2];
  #pragma unroll
  for (int ds = 0; ds < 2; ds++)
    aq[ds] = *reinterpret_cast<const bf16x8*>(
        &QKV[(rowb + qt * 64 + w * 16 + llo) * QKVW + h * 64 + ds * 32 + lhi * 8]);

  // frag-major staging sources (chunk c = iss*256 + t)
  const int cA = t, cB = 256 + t;
  const int gA = cA >> 6, lA = cA & 63, gB = cB >> 6, lB = cB & 63;
  const unsigned short* kpA = &QKV[(rowb + (gA >> 1) * 16 + (lA & 15)) * QKVW + kcol + (gA & 1) * 32 + (lA >> 4) * 8];
  const unsigned short* kpB = &QKV[(rowb + (gB >> 1) * 16 + (lB & 15)) * QKVW + kcol + (gB & 1) * 32 + (lB >> 4) * 8];
  const unsigned short* vpA = &VT[vtb + (size_t)((gA >> 1) * 16 + (lA & 15)) * SEQ + (gA & 1) * 32 + (lA >> 4) * 8];
  const unsigned short* vpB = &VT[vtb + (size_t)((gB >> 1) * 16 + (lB & 15)) * SEQ + (gB & 1) * 32 + (lB >> 4) * 8];

#define ASTAGE(KsX, VsX, ktt) do { \
    gl16(kpA + (size_t)(ktt) * 64 * QKVW, &KsX[cA * 8]); \
    gl16(kpB + (size_t)(ktt) * 64 * QKVW, &KsX[cB * 8]); \
    gl16(vpA + (ktt) * 64, &VsX[cA * 8]); \
    gl16(vpB + (ktt) * 64, &VsX[cB * 8]); \
  } while (0)

  const int psbase = w * 1024 + llo * 64;
  const int lsw = llo & 7;

#define ACOMP(KsX, VsX) do { \
    f32x4 s_[4]; \
    _Pragma("unroll") \
    for (int fj = 0; fj < 4; fj++) \
      _Pragma("unroll") \
      for (int i = 0; i < 4; i++) s_[fj][i] = -16.0f; \
    _Pragma("unroll") \
    for (int ds = 0; ds < 2; ds++) \
      _Pragma("unroll") \
      for (int fj = 0; fj < 4; fj++) { \
        bf16x8 bk = *reinterpret_cast<const bf16x8*>(&KsX[((fj * 2 + ds) * 64 + lane) * 8]); \
        s_[fj] = __builtin_amdgcn_mfma_f32_16x16x32_bf16(bk, aq[ds], s_[fj], 0, 0, 0); \
      } \
    _Pragma("unroll") \
    for (int fj = 0; fj < 4; fj++) { \
      const float p0 = exp2_fast(s_[fj][0]); \
      const float p1 = exp2_fast(s_[fj][1]); \
      const float p2 = exp2_fast(s_[fj][2]); \
      const float p3 = exp2_fast(s_[fj][3]); \
      l_ += (p0 + p1) + (p2 + p3); \
      uint2 uv; uv.x = cvtpk_bf16(p0, p1); uv.y = cvtpk_bf16(p2, p3); \
      const int pg = ((fj << 1) | (lhi >> 1)) ^ lsw; \
      *reinterpret_cast<uint2*>(&Ps[psbase + pg * 8 + (lhi & 1) * 4]) = uv; \
    } \
    _Pragma("unroll") \
    for (int ks = 0; ks < 2; ks++) { \
      bf16x8 ap = *reinterpret_cast<const bf16x8*>(&Ps[psbase + ((((ks << 2) | lhi) ^ lsw) << 3)]); \
      _Pragma("unroll") \
      for (int fo = 0; fo < 4; fo++) { \
        bf16x8 bv = *reinterpret_cast<const bf16x8*>(&VsX[((fo * 2 + ks) * 64 + lane) * 8]); \
        o_[fo] = __builtin_amdgcn_mfma_f32_16x16x32_bf16(ap, bv, o_[fo], 0, 0, 0); \
      } \
    } \
  } while (0)

  float l_ = 0.0f;
  f32x4 o_[4] = {};

  ASTAGE(Ks0, Vs0, 0);
  for (int kt = 0; kt < 16; kt += 2) {
    __syncthreads();
    ASTAGE(Ks1, Vs1, kt + 1);
    ACOMP(Ks0, Vs0);
    __syncthreads();
    if (kt + 2 < 16) ASTAGE(Ks0, Vs0, kt + 2);
    ACOMP(Ks1, Vs1);
  }
#undef ASTAGE
#undef ACOMP

  // l_ holds partial denom for q=llo; reduce across the 4 lhi lanes
  l_ += __shfl_xor(l_, 16);
  l_ += __shfl_xor(l_, 32);
  const float linv = 1.0f / l_;   // valid at q=llo (replicated across lhi)

  #pragma unroll
  for (int i = 0; i < 4; i++) {
    const float li = __shfl(linv, lhi * 4 + i);   // linv for q=lhi*4+i
    #pragma unroll
    for (int fo = 0; fo < 4; fo++) {
      const float v = o_[fo][i] * li;
      Zb[(rowb + qt * 64 + w * 16 + lhi * 4 + i) * 512 + h * 64 + fo * 16 + llo] = f2bf(v);
    }
  }
}

// ---------------------------------------------------------------- driver
extern "C" void kernel_launch(void* const* d_in, const int* in_sizes, int n_in,
                              void* d_out, int out_size, void* d_ws, size_t ws_size,
                              hipStream_t stream)
{
  const float* x   = (const float*)d_in[0];
  const float* Wq  = (const float*)d_in[1];
  const float* Wk  = (const float*)d_in[2];
  const float* Wv  = (const float*)d_in[3];
  const float* Wo  = (const float*)d_in[4];
  const float* W1  = (const float*)d_in[5];
  const float* b1  = (const float*)d_in[6];
  const float* W2  = (const float*)d_in[7];
  const float* b2  = (const float*)d_in[8];
  const float* ga  = (const float*)d_in[9];
  const float* ba  = (const float*)d_in[10];
  const float* gf  = (const float*)d_in[11];
  const float* bfn = (const float*)d_in[12];
  float* out = (float*)d_out;

  char* p = (char*)d_ws;
  auto alloc = [&](size_t bytes) { void* r = (void*)p; p += (bytes + 255) & ~(size_t)255; return r; };
  float* E0 = (float*)alloc((size_t)ROWS * 512 * 4);
  float* E1 = (float*)alloc((size_t)ROWS * 512 * 4);
  unsigned short* Ybf   = (unsigned short*)alloc((size_t)ROWS * 512 * 2);
  unsigned short* QKVbf = (unsigned short*)alloc((size_t)ROWS * QKVW * 2);
  unsigned short* H1bf  = (unsigned short*)alloc((size_t)ROWS * 2048 * 2);
  unsigned short* VT    = H1bf;   // aliases front 8MB of H1bf (disjoint in time)
  unsigned short* WtQKV = (unsigned short*)alloc(6ull * QKVW * 512 * 2);
  unsigned short* WtO   = (unsigned short*)alloc(6ull * 512 * 512 * 2);
  unsigned short* Wt1   = (unsigned short*)alloc(6ull * 2048 * 512 * 2);
  unsigned short* Wt2   = (unsigned short*)alloc(6ull * 512 * 2048 * 2);
  unsigned short* Zbf   = Ybf;

  // weight prep (Wq carries softmax scale AND log2e for exp2-domain softmax)
  const float qscale = 0.125f * 1.44269504f;
  transpose_cast_k<<<dim3(16, 16, 6), 256, 0, stream>>>(Wq, WtQKV,          512, 512,  QKVW * 512, qscale);
  transpose_cast_k<<<dim3(16, 16, 6), 256, 0, stream>>>(Wk, WtQKV + 262144, 512, 512,  QKVW * 512, 1.0f);
  transpose_cast_k<<<dim3(16, 16, 6), 256, 0, stream>>>(Wv, WtQKV + 524288, 512, 512,  QKVW * 512, 1.0f);
  transpose_cast_k<<<dim3(16, 16, 6), 256, 0, stream>>>(Wo, WtO,            512, 512,  262144,     1.0f);
  transpose_cast_k<<<dim3(64, 16, 6), 256, 0, stream>>>(W1, Wt1,            512, 2048, 1048576,    1.0f);
  transpose_cast_k<<<dim3(16, 64, 6), 256, 0, stream>>>(W2, Wt2,            2048, 512, 1048576,    1.0f);

  for (int l = 0; l < 6; l++) {
    const float* enc = (l == 0) ? x : E0;
    // pre-LN attention
    ln_k<<<2048, 256, 0, stream>>>(enc, ga + l * 512, ba + l * 512, Ybf, ROWS);
    gemm128_k<false, false, false, true><<<dim3(12, 64), 256, 0, stream>>>(
        Ybf, WtQKV + (size_t)l * QKVW * 512, nullptr, nullptr, QKVbf, ROWS, QKVW, 512);
    vtrans_k<<<dim3(16, 64), 256, 0, stream>>>(QKVbf, VT);
    attn_k<<<dim3(16, 8, 8), 256, 0, stream>>>(QKVbf, VT, Zbf);
    gemm64_k<false, false, true, false><<<dim3(4, 128), 256, 0, stream>>>(
        Zbf, WtO + (size_t)l * 262144, nullptr, enc, E1, ROWS, 512, 512);
    // pre-LN FFN
    ln_k<<<2048, 256, 0, stream>>>(E1, gf + l * 512, bfn + l * 512, Ybf, ROWS);
    gemm128_k<true, true, false, true><<<dim3(16, 64), 256, 0, stream>>>(
        Ybf, Wt1 + (size_t)l * 1048576, b1 + l * 2048, nullptr, H1bf, ROWS, 2048, 512);
    gemm64_k<false, true, true, false><<<dim3(4, 128), 256, 0, stream>>>(
        H1bf, Wt2 + (size_t)l * 1048576, b2 + l * 512, E1, (l == 5) ? out : E0,
        ROWS, 512, 2048);
  }
}

// Round 9
// 818.408 us; speedup vs baseline: 1.6456x; 1.0799x over previous
//
#include <hip/hip_runtime.h>

// 6-layer pre-LN encoder, B=8 S=1024 D=512 H=8 DH=64 FFN=2048.
// Round 9: attention v5 — 32 q-rows per wave (128/block, grid 512): halves
// LDS-pipe cycles per MFMA (K/V frags reused by 2 q-groups); grid laid out
// (h, qt, b) so all q-tiles of a (b,h) share an XCD L2. GEMMs unchanged.

#define SEQ 1024
#define ROWS 8192
#define QKVW 1536

using bf16x8 = __attribute__((ext_vector_type(8))) short;
using f32x4  = __attribute__((ext_vector_type(4))) float;

__device__ __forceinline__ unsigned short f2bf(float f) {
  union { float f; unsigned u; } v; v.f = f;
  unsigned r = v.u + 0x7FFFu + ((v.u >> 16) & 1u);   // RNE
  return (unsigned short)(r >> 16);
}

__device__ __forceinline__ float exp2_fast(float x) {
  float r;
  asm("v_exp_f32 %0, %1" : "=v"(r) : "v"(x));
  return r;
}

__device__ __forceinline__ unsigned cvtpk_bf16(float a, float b) {
  unsigned r;   // low16 = bf16(a), high16 = bf16(b)
  asm("v_cvt_pk_bf16_f32 %0, %1, %2" : "=v"(r) : "v"(a), "v"(b));
  return r;
}

__device__ __forceinline__ void gl16(const void* g, void* l) {
  typedef const unsigned int __attribute__((address_space(1)))* GP;
  typedef unsigned int __attribute__((address_space(3)))* LP;
  __builtin_amdgcn_global_load_lds((GP)g, (LP)l, 16, 0, 0);
}

// ---------------------------------------------------------------- weight prep
__global__ __launch_bounds__(256) void transpose_cast_k(
    const float* __restrict__ W, unsigned short* __restrict__ Wt,
    int K, int N, int lstride, float scale)
{
  __shared__ float tile[32][33];
  const int l = blockIdx.z;
  const float* Wl = W + (size_t)l * K * N;
  unsigned short* Wtl = Wt + (size_t)l * lstride;
  const int k0 = blockIdx.y * 32, n0 = blockIdx.x * 32;
  const int tx = threadIdx.x & 31, ty = threadIdx.x >> 5;
  #pragma unroll
  for (int i = ty; i < 32; i += 8)
    tile[i][tx] = Wl[(size_t)(k0 + i) * N + n0 + tx];
  __syncthreads();
  #pragma unroll
  for (int i = ty; i < 32; i += 8)
    Wtl[(size_t)(n0 + i) * K + k0 + tx] = f2bf(tile[tx][i] * scale);
}

// ---------------------------------------------------------------- layernorm
__global__ __launch_bounds__(256) void ln_k(
    const float* __restrict__ x, const float* __restrict__ g,
    const float* __restrict__ be, unsigned short* __restrict__ y, int rows)
{
  const int wid = (blockIdx.x << 2) | (threadIdx.x >> 6);
  const int lane = threadIdx.x & 63;
  if (wid >= rows) return;
  const float4* xr = reinterpret_cast<const float4*>(x + (size_t)wid * 512);
  float4 a = xr[lane];
  float4 b = xr[lane + 64];
  float s = a.x + a.y + a.z + a.w + b.x + b.y + b.z + b.w;
  #pragma unroll
  for (int m = 32; m >= 1; m >>= 1) s += __shfl_xor(s, m);
  const float mu = s * (1.0f / 512.0f);
  const float d0 = a.x - mu, d1 = a.y - mu, d2 = a.z - mu, d3 = a.w - mu;
  const float e0 = b.x - mu, e1 = b.y - mu, e2 = b.z - mu, e3 = b.w - mu;
  float q = d0*d0 + d1*d1 + d2*d2 + d3*d3 + e0*e0 + e1*e1 + e2*e2 + e3*e3;
  #pragma unroll
  for (int m = 32; m >= 1; m >>= 1) q += __shfl_xor(q, m);
  const float inv = rsqrtf(q * (1.0f / 512.0f) + 1e-3f);
  const float4* gr = reinterpret_cast<const float4*>(g);
  const float4* br = reinterpret_cast<const float4*>(be);
  const float4 g0 = gr[lane], g1 = gr[lane + 64];
  const float4 h0 = br[lane], h1 = br[lane + 64];
  ushort4 o0, o1;
  o0.x = f2bf(d0 * inv * g0.x + h0.x);
  o0.y = f2bf(d1 * inv * g0.y + h0.y);
  o0.z = f2bf(d2 * inv * g0.z + h0.z);
  o0.w = f2bf(d3 * inv * g0.w + h0.w);
  o1.x = f2bf(e0 * inv * g1.x + h1.x);
  o1.y = f2bf(e1 * inv * g1.y + h1.y);
  o1.z = f2bf(e2 * inv * g1.z + h1.z);
  o1.w = f2bf(e3 * inv * g1.w + h1.w);
  *reinterpret_cast<ushort4*>(y + (size_t)wid * 512 + lane * 4) = o0;
  *reinterpret_cast<ushort4*>(y + (size_t)wid * 512 + (lane + 64) * 4) = o1;
}

// ---------------------------------------------------------------- GEMM 128x128, BK=32, dbuf 2-phase
template<bool RELU, bool HASBIAS, bool HASRES, bool OUTBF>
__global__ __launch_bounds__(256) void gemm128_k(
    const unsigned short* __restrict__ A,
    const unsigned short* __restrict__ Wt,
    const float* __restrict__ bias,
    const float* __restrict__ res,
    void* __restrict__ outp, int M, int N, int K)
{
  __shared__ __align__(16) unsigned short As0[4096], Bs0[4096];
  __shared__ __align__(16) unsigned short As1[4096], Bs1[4096];
  const int t = threadIdx.x;
  const int nwg = gridDim.x * gridDim.y;
  const int bid = blockIdx.y * gridDim.x + blockIdx.x;
  const int nid = (bid & 7) * (nwg >> 3) + (bid >> 3);
  const int bx = nid % gridDim.x, by = nid / gridDim.x;
  const int m0 = by * 128, n0 = bx * 128;
  const int w = t >> 6, lane = t & 63, llo = lane & 15, lhi = lane >> 4;
  const int wr = w >> 1, wc = w & 1;

  const int sr = t >> 2, sg = (t & 3) ^ ((t >> 3) & 3);
  const unsigned short* pa = &A[(size_t)(m0 + sr) * K + sg * 8];
  const unsigned short* pb = &Wt[(size_t)(n0 + sr) * K + sg * 8];

#define GSTAGE128(AsX, BsX, koff) do { \
    gl16(pa + (koff), &AsX[t * 8]); \
    gl16(pa + (size_t)64 * K + (koff), &AsX[2048 + t * 8]); \
    gl16(pb + (koff), &BsX[t * 8]); \
    gl16(pb + (size_t)64 * K + (koff), &BsX[2048 + t * 8]); \
  } while (0)

  const int pgo = (lhi ^ ((llo >> 1) & 3)) * 8;

#define GCOMP128(AsX, BsX) do { \
    bf16x8 af[4], bfr[4]; \
    _Pragma("unroll") \
    for (int f = 0; f < 4; f++) { \
      af[f]  = *reinterpret_cast<const bf16x8*>(&AsX[(wr * 64 + f * 16 + llo) * 32 + pgo]); \
      bfr[f] = *reinterpret_cast<const bf16x8*>(&BsX[(wc * 64 + f * 16 + llo) * 32 + pgo]); \
    } \
    _Pragma("unroll") \
    for (int fi = 0; fi < 4; fi++) \
      _Pragma("unroll") \
      for (int fj = 0; fj < 4; fj++) \
        acc[fi][fj] = __builtin_amdgcn_mfma_f32_16x16x32_bf16(af[fi], bfr[fj], acc[fi][fj], 0, 0, 0); \
  } while (0)

  f32x4 acc[4][4] = {};
  GSTAGE128(As0, Bs0, 0);
  for (int k0 = 0; k0 < K; k0 += 64) {
    __syncthreads();
    GSTAGE128(As1, Bs1, k0 + 32);
    GCOMP128(As0, Bs0);
    __syncthreads();
    if (k0 + 64 < K) GSTAGE128(As0, Bs0, k0 + 64);
    GCOMP128(As1, Bs1);
  }
#undef GSTAGE128
#undef GCOMP128

  const int row0 = m0 + wr * 64, col0 = n0 + wc * 64;
  #pragma unroll
  for (int fi = 0; fi < 4; fi++)
    #pragma unroll
    for (int fj = 0; fj < 4; fj++)
      #pragma unroll
      for (int i = 0; i < 4; i++) {
        const int row = row0 + fi * 16 + lhi * 4 + i;
        const int col = col0 + fj * 16 + llo;
        float v = acc[fi][fj][i];
        if (HASBIAS) v += bias[col];
        if (HASRES)  v += res[(size_t)row * N + col];
        if (RELU)    v = fmaxf(v, 0.0f);
        if (OUTBF) ((unsigned short*)outp)[(size_t)row * N + col] = f2bf(v);
        else       ((float*)outp)[(size_t)row * N + col] = v;
      }
}

// ---------------------------------------------------------------- GEMM 64x128, BK=32, dbuf 2-phase
template<bool RELU, bool HASBIAS, bool HASRES, bool OUTBF>
__global__ __launch_bounds__(256) void gemm64_k(
    const unsigned short* __restrict__ A,
    const unsigned short* __restrict__ Wt,
    const float* __restrict__ bias,
    const float* __restrict__ res,
    void* __restrict__ outp, int M, int N, int K)
{
  __shared__ __align__(16) unsigned short As0[2048], Bs0[4096];
  __shared__ __align__(16) unsigned short As1[2048], Bs1[4096];
  const int t = threadIdx.x;
  const int nwg = gridDim.x * gridDim.y;
  const int bid = blockIdx.y * gridDim.x + blockIdx.x;
  const int nid = (bid & 7) * (nwg >> 3) + (bid >> 3);
  const int bx = nid % gridDim.x, by = nid / gridDim.x;
  const int m0 = by * 64, n0 = bx * 128;
  const int w = t >> 6, lane = t & 63, llo = lane & 15, lhi = lane >> 4;
  const int wr = w >> 1, wc = w & 1;

  const int sr = t >> 2, sg = (t & 3) ^ ((t >> 3) & 3);
  const unsigned short* pa = &A[(size_t)(m0 + sr) * K + sg * 8];
  const unsigned short* pb = &Wt[(size_t)(n0 + sr) * K + sg * 8];

#define GSTAGE64(AsX, BsX, koff) do { \
    gl16(pa + (koff), &AsX[t * 8]); \
    gl16(pb + (koff), &BsX[t * 8]); \
    gl16(pb + (size_t)64 * K + (koff), &BsX[2048 + t * 8]); \
  } while (0)

  const int pgo = (lhi ^ ((llo >> 1) & 3)) * 8;

#define GCOMP64(AsX, BsX) do { \
    bf16x8 af[2], bfr[4]; \
    _Pragma("unroll") \
    for (int f = 0; f < 2; f++) \
      af[f] = *reinterpret_cast<const bf16x8*>(&AsX[(wr * 32 + f * 16 + llo) * 32 + pgo]); \
    _Pragma("unroll") \
    for (int f = 0; f < 4; f++) \
      bfr[f] = *reinterpret_cast<const bf16x8*>(&BsX[(wc * 64 + f * 16 + llo) * 32 + pgo]); \
    _Pragma("unroll") \
    for (int fi = 0; fi < 2; fi++) \
      _Pragma("unroll") \
      for (int fj = 0; fj < 4; fj++) \
        acc[fi][fj] = __builtin_amdgcn_mfma_f32_16x16x32_bf16(af[fi], bfr[fj], acc[fi][fj], 0, 0, 0); \
  } while (0)

  f32x4 acc[2][4] = {};
  GSTAGE64(As0, Bs0, 0);
  for (int k0 = 0; k0 < K; k0 += 64) {
    __syncthreads();
    GSTAGE64(As1, Bs1, k0 + 32);
    GCOMP64(As0, Bs0);
    __syncthreads();
    if (k0 + 64 < K) GSTAGE64(As0, Bs0, k0 + 64);
    GCOMP64(As1, Bs1);
  }
#undef GSTAGE64
#undef GCOMP64

  const int row0 = m0 + wr * 32, col0 = n0 + wc * 64;
  #pragma unroll
  for (int fi = 0; fi < 2; fi++)
    #pragma unroll
    for (int fj = 0; fj < 4; fj++)
      #pragma unroll
      for (int i = 0; i < 4; i++) {
        const int row = row0 + fi * 16 + lhi * 4 + i;
        const int col = col0 + fj * 16 + llo;
        float v = acc[fi][fj][i];
        if (HASBIAS) v += bias[col];
        if (HASRES)  v += res[(size_t)row * N + col];
        if (RELU)    v = fmaxf(v, 0.0f);
        if (OUTBF) ((unsigned short*)outp)[(size_t)row * N + col] = f2bf(v);
        else       ((float*)outp)[(size_t)row * N + col] = v;
      }
}

// ---------------------------------------------------------------- V transpose
__global__ __launch_bounds__(256) void vtrans_k(
    const unsigned short* __restrict__ QKV, unsigned short* __restrict__ VT)
{
  __shared__ unsigned short tile[64][66];
  const int kt = blockIdx.x, bh = blockIdx.y;
  const int bb = bh >> 3, h = bh & 7;
  const int t = threadIdx.x;
  const int r = t >> 2, c0 = (t & 3) * 16;
  const unsigned short* src = &QKV[((size_t)bb * SEQ + kt * 64 + r) * QKVW + 1024 + h * 64 + c0];
  *reinterpret_cast<uint4*>(&tile[r][c0])     = *reinterpret_cast<const uint4*>(src);
  *reinterpret_cast<uint4*>(&tile[r][c0 + 8]) = *reinterpret_cast<const uint4*>(src + 8);
  __syncthreads();
  const int dv = t >> 2, kv0 = (t & 3) * 16;
  unsigned short tmp[16];
  #pragma unroll
  for (int j = 0; j < 16; j++) tmp[j] = tile[kv0 + j][dv];
  ushort4 o0, o1, o2, o3;
  o0.x = tmp[0];  o0.y = tmp[1];  o0.z = tmp[2];  o0.w = tmp[3];
  o1.x = tmp[4];  o1.y = tmp[5];  o1.z = tmp[6];  o1.w = tmp[7];
  o2.x = tmp[8];  o2.y = tmp[9];  o2.z = tmp[10]; o2.w = tmp[11];
  o3.x = tmp[12]; o3.y = tmp[13]; o3.z = tmp[14]; o3.w = tmp[15];
  unsigned short* dst = &VT[((size_t)bh * 64 + dv) * SEQ + kt * 64 + kv0];
  *reinterpret_cast<ushort4*>(dst)      = o0;
  *reinterpret_cast<ushort4*>(dst + 4)  = o1;
  *reinterpret_cast<ushort4*>(dst + 8)  = o2;
  *reinterpret_cast<ushort4*>(dst + 12) = o3;
}

// ---------------------------------------------------------------- attention v5
// grid (h, qt, b): linear id = h mod 8 -> all q-tiles of a (b,h) on one XCD.
// 4 waves x 32 q-rows (128/block); kv tiles of 64; K/V dbuf 2-phase. Swapped
// QK^T (S^T = mfma(K,Q)); P via cvt_pk + ds_write_b64, granule-XOR per-wave
// [32][64] buffer; K/V frags reused by both 16-q groups. Static-max log2
// softmax (Q pre-scaled by 0.125*log2e, acc init -16).
__global__ __launch_bounds__(256) void attn_k(
    const unsigned short* __restrict__ QKV,   // [8192][1536]
    const unsigned short* __restrict__ VT,    // [bh][64][1024]
    unsigned short* __restrict__ Zb)          // [8192][512]
{
  __shared__ __align__(16) unsigned short Ks0[4096], Vs0[4096];
  __shared__ __align__(16) unsigned short Ks1[4096], Vs1[4096];
  __shared__ __align__(16) unsigned short Ps[8192];   // 4 waves x [32][64]

  const int t = threadIdx.x;
  const int h = blockIdx.x, qt = blockIdx.y, bb = blockIdx.z;
  const int w = t >> 6, lane = t & 63, llo = lane & 15, lhi = lane >> 4;
  const size_t rowb = (size_t)bb * SEQ;
  const int kcol = 512 + h * 64;
  const size_t vtb = (size_t)(bb * 8 + h) * 64 * SEQ;

  // hoist Q fragments (0.125*log2e folded into Wq); 32 q rows per wave
  bf16x8 aq[2][2];
  #pragma unroll
  for (int mi = 0; mi < 2; mi++)
    #pragma unroll
    for (int ds = 0; ds < 2; ds++)
      aq[mi][ds] = *reinterpret_cast<const bf16x8*>(
          &QKV[(rowb + qt * 128 + w * 32 + mi * 16 + llo) * QKVW + h * 64 + ds * 32 + lhi * 8]);

  // frag-major staging sources (chunk c = iss*256 + t)
  const int cA = t, cB = 256 + t;
  const int gA = cA >> 6, lA = cA & 63, gB = cB >> 6, lB = cB & 63;
  const unsigned short* kpA = &QKV[(rowb + (gA >> 1) * 16 + (lA & 15)) * QKVW + kcol + (gA & 1) * 32 + (lA >> 4) * 8];
  const unsigned short* kpB = &QKV[(rowb + (gB >> 1) * 16 + (lB & 15)) * QKVW + kcol + (gB & 1) * 32 + (lB >> 4) * 8];
  const unsigned short* vpA = &VT[vtb + (size_t)((gA >> 1) * 16 + (lA & 15)) * SEQ + (gA & 1) * 32 + (lA >> 4) * 8];
  const unsigned short* vpB = &VT[vtb + (size_t)((gB >> 1) * 16 + (lB & 15)) * SEQ + (gB & 1) * 32 + (lB >> 4) * 8];

#define ASTAGE(KsX, VsX, ktt) do { \
    gl16(kpA + (size_t)(ktt) * 64 * QKVW, &KsX[cA * 8]); \
    gl16(kpB + (size_t)(ktt) * 64 * QKVW, &KsX[cB * 8]); \
    gl16(vpA + (ktt) * 64, &VsX[cA * 8]); \
    gl16(vpB + (ktt) * 64, &VsX[cB * 8]); \
  } while (0)

  const int psw = w * 2048;      // per-wave [32][64] region (shorts)
  const int lsw = llo & 7;

#define ACOMP(KsX, VsX) do { \
    f32x4 s_[2][4]; \
    _Pragma("unroll") \
    for (int mi = 0; mi < 2; mi++) \
      _Pragma("unroll") \
      for (int fj = 0; fj < 4; fj++) \
        _Pragma("unroll") \
        for (int i = 0; i < 4; i++) s_[mi][fj][i] = -16.0f; \
    _Pragma("unroll") \
    for (int ds = 0; ds < 2; ds++) \
      _Pragma("unroll") \
      for (int fj = 0; fj < 4; fj++) { \
        bf16x8 bk = *reinterpret_cast<const bf16x8*>(&KsX[((fj * 2 + ds) * 64 + lane) * 8]); \
        s_[0][fj] = __builtin_amdgcn_mfma_f32_16x16x32_bf16(bk, aq[0][ds], s_[0][fj], 0, 0, 0); \
        s_[1][fj] = __builtin_amdgcn_mfma_f32_16x16x32_bf16(bk, aq[1][ds], s_[1][fj], 0, 0, 0); \
      } \
    _Pragma("unroll") \
    for (int mi = 0; mi < 2; mi++) \
      _Pragma("unroll") \
      for (int fj = 0; fj < 4; fj++) { \
        const float p0 = exp2_fast(s_[mi][fj][0]); \
        const float p1 = exp2_fast(s_[mi][fj][1]); \
        const float p2 = exp2_fast(s_[mi][fj][2]); \
        const float p3 = exp2_fast(s_[mi][fj][3]); \
        l_[mi] += (p0 + p1) + (p2 + p3); \
        uint2 uv; uv.x = cvtpk_bf16(p0, p1); uv.y = cvtpk_bf16(p2, p3); \
        const int pg = ((fj << 1) | (lhi >> 1)) ^ lsw; \
        *reinterpret_cast<uint2*>(&Ps[psw + (mi * 16 + llo) * 64 + pg * 8 + (lhi & 1) * 4]) = uv; \
      } \
    _Pragma("unroll") \
    for (int ks = 0; ks < 2; ks++) { \
      const int prg = (((ks << 2) | lhi) ^ lsw) << 3; \
      bf16x8 ap0 = *reinterpret_cast<const bf16x8*>(&Ps[psw + llo * 64 + prg]); \
      bf16x8 ap1 = *reinterpret_cast<const bf16x8*>(&Ps[psw + (16 + llo) * 64 + prg]); \
      _Pragma("unroll") \
      for (int fo = 0; fo < 4; fo++) { \
        bf16x8 bv = *reinterpret_cast<const bf16x8*>(&VsX[((fo * 2 + ks) * 64 + lane) * 8]); \
        o_[0][fo] = __builtin_amdgcn_mfma_f32_16x16x32_bf16(ap0, bv, o_[0][fo], 0, 0, 0); \
        o_[1][fo] = __builtin_amdgcn_mfma_f32_16x16x32_bf16(ap1, bv, o_[1][fo], 0, 0, 0); \
      } \
    } \
  } while (0)

  float l_[2] = {0.0f, 0.0f};
  f32x4 o_[2][4] = {};

  ASTAGE(Ks0, Vs0, 0);
  for (int kt = 0; kt < 16; kt += 2) {
    __syncthreads();
    ASTAGE(Ks1, Vs1, kt + 1);
    ACOMP(Ks0, Vs0);
    __syncthreads();
    if (kt + 2 < 16) ASTAGE(Ks0, Vs0, kt + 2);
    ACOMP(Ks1, Vs1);
  }
#undef ASTAGE
#undef ACOMP

  // l_[mi] holds partial denom for q=llo (group mi); reduce across lhi lanes
  #pragma unroll
  for (int mi = 0; mi < 2; mi++) {
    l_[mi] += __shfl_xor(l_[mi], 16);
    l_[mi] += __shfl_xor(l_[mi], 32);
    l_[mi] = 1.0f / l_[mi];
  }

  #pragma unroll
  for (int mi = 0; mi < 2; mi++)
    #pragma unroll
    for (int i = 0; i < 4; i++) {
      const float li = __shfl(l_[mi], lhi * 4 + i);   // linv for q=lhi*4+i
      #pragma unroll
      for (int fo = 0; fo < 4; fo++) {
        const float v = o_[mi][fo][i] * li;
        Zb[(rowb + qt * 128 + w * 32 + mi * 16 + lhi * 4 + i) * 512 + h * 64 + fo * 16 + llo] = f2bf(v);
      }
    }
}

// ---------------------------------------------------------------- driver
extern "C" void kernel_launch(void* const* d_in, const int* in_sizes, int n_in,
                              void* d_out, int out_size, void* d_ws, size_t ws_size,
                              hipStream_t stream)
{
  const float* x   = (const float*)d_in[0];
  const float* Wq  = (const float*)d_in[1];
  const float* Wk  = (const float*)d_in[2];
  const float* Wv  = (const float*)d_in[3];
  const float* Wo  = (const float*)d_in[4];
  const float* W1  = (const float*)d_in[5];
  const float* b1  = (const float*)d_in[6];
  const float* W2  = (const float*)d_in[7];
  const float* b2  = (const float*)d_in[8];
  const float* ga  = (const float*)d_in[9];
  const float* ba  = (const float*)d_in[10];
  const float* gf  = (const float*)d_in[11];
  const float* bfn = (const float*)d_in[12];
  float* out = (float*)d_out;

  char* p = (char*)d_ws;
  auto alloc = [&](size_t bytes) { void* r = (void*)p; p += (bytes + 255) & ~(size_t)255; return r; };
  float* E0 = (float*)alloc((size_t)ROWS * 512 * 4);
  float* E1 = (float*)alloc((size_t)ROWS * 512 * 4);
  unsigned short* Ybf   = (unsigned short*)alloc((size_t)ROWS * 512 * 2);
  unsigned short* QKVbf = (unsigned short*)alloc((size_t)ROWS * QKVW * 2);
  unsigned short* H1bf  = (unsigned short*)alloc((size_t)ROWS * 2048 * 2);
  unsigned short* VT    = H1bf;   // aliases front 8MB of H1bf (disjoint in time)
  unsigned short* WtQKV = (unsigned short*)alloc(6ull * QKVW * 512 * 2);
  unsigned short* WtO   = (unsigned short*)alloc(6ull * 512 * 512 * 2);
  unsigned short* Wt1   = (unsigned short*)alloc(6ull * 2048 * 512 * 2);
  unsigned short* Wt2   = (unsigned short*)alloc(6ull * 512 * 2048 * 2);
  unsigned short* Zbf   = Ybf;

  // weight prep (Wq carries softmax scale AND log2e for exp2-domain softmax)
  const float qscale = 0.125f * 1.44269504f;
  transpose_cast_k<<<dim3(16, 16, 6), 256, 0, stream>>>(Wq, WtQKV,          512, 512,  QKVW * 512, qscale);
  transpose_cast_k<<<dim3(16, 16, 6), 256, 0, stream>>>(Wk, WtQKV + 262144, 512, 512,  QKVW * 512, 1.0f);
  transpose_cast_k<<<dim3(16, 16, 6), 256, 0, stream>>>(Wv, WtQKV + 524288, 512, 512,  QKVW * 512, 1.0f);
  transpose_cast_k<<<dim3(16, 16, 6), 256, 0, stream>>>(Wo, WtO,            512, 512,  262144,     1.0f);
  transpose_cast_k<<<dim3(64, 16, 6), 256, 0, stream>>>(W1, Wt1,            512, 2048, 1048576,    1.0f);
  transpose_cast_k<<<dim3(16, 64, 6), 256, 0, stream>>>(W2, Wt2,            2048, 512, 1048576,    1.0f);

  for (int l = 0; l < 6; l++) {
    const float* enc = (l == 0) ? x : E0;
    // pre-LN attention
    ln_k<<<2048, 256, 0, stream>>>(enc, ga + l * 512, ba + l * 512, Ybf, ROWS);
    gemm128_k<false, false, false, true><<<dim3(12, 64), 256, 0, stream>>>(
        Ybf, WtQKV + (size_t)l * QKVW * 512, nullptr, nullptr, QKVbf, ROWS, QKVW, 512);
    vtrans_k<<<dim3(16, 64), 256, 0, stream>>>(QKVbf, VT);
    attn_k<<<dim3(8, 8, 8), 256, 0, stream>>>(QKVbf, VT, Zbf);
    gemm64_k<false, false, true, false><<<dim3(4, 128), 256, 0, stream>>>(
        Zbf, WtO + (size_t)l * 262144, nullptr, enc, E1, ROWS, 512, 512);
    // pre-LN FFN
    ln_k<<<2048, 256, 0, stream>>>(E1, gf + l * 512, bfn + l * 512, Ybf, ROWS);
    gemm128_k<true, true, false, true><<<dim3(16, 64), 256, 0, stream>>>(
        Ybf, Wt1 + (size_t)l * 1048576, b1 + l * 2048, nullptr, H1bf, ROWS, 2048, 512);
    gemm64_k<false, true, true, false><<<dim3(4, 128), 256, 0, stream>>>(
        H1bf, Wt2 + (size_t)l * 1048576, b2 + l * 512, E1, (l == 5) ? out : E0,
        ROWS, 512, 2048);
  }
}